// Round 4
// baseline (338.840 us; speedup 1.0000x reference)
//
#include <hip/hip_runtime.h>
#include <hip/hip_bf16.h>

#define BB 65536
#define NFIELD 20
#define DATA_NEMB 10
#define SQL_NEMB 10
#define HID 64
#define KEXP 16
#define EPS 1e-5f
#define NBLK_GATE 512
#define NCHUNK (BB / 64)
#define GATE_IN (NFIELD * SQL_NEMB)
#define EXP_IN (NFIELD * DATA_NEMB)

// ---- ws layout (element offsets, 4B elements) ----
#define OFF_GCNT 0                      // 16 int
#define OFF_SC1 64                      // 16*64 f32
#define OFF_SH1 (OFF_SC1 + 1024)
#define OFF_SC2 (OFF_SH1 + 1024)
#define OFF_SH2 (OFF_SC2 + 1024)
#define OFF_SCP (OFF_SH2 + 1024)        // 64
#define OFF_SHP (OFF_SCP + 64)          // 64
#define OFF_IMP (OFF_SHP + 64)          // 512*16 importance partials
#define OFF_LIDX (OFF_IMP + 8192)       // 16*B int
#define OFF_LW (OFF_LIDX + (16 * BB))   // 16*B f32
#define OFF_HS (OFF_LW + (16 * BB))     // 2B*64 f32 (weighted h2 per slot)
#define OFF_H1 (OFF_HS + (2 * BB * 64)) // 2B*64 f32 (h1 per slot)

// ---------------- prep: BN folds + counter zero ----------------
__global__ __launch_bounds__(256) void k_prep(
    const float* __restrict__ eb1, const float* __restrict__ eg1,
    const float* __restrict__ ebe1, const float* __restrict__ em1,
    const float* __restrict__ ev1,
    const float* __restrict__ eb2, const float* __restrict__ eg2,
    const float* __restrict__ ebe2, const float* __restrict__ em2,
    const float* __restrict__ ev2,
    const float* __restrict__ pb1, const float* __restrict__ pg,
    const float* __restrict__ pbe, const float* __restrict__ pm,
    const float* __restrict__ pv,
    float* __restrict__ wsf, int* __restrict__ gcnt)
{
    int gid = blockIdx.x * 256 + threadIdx.x;
    if (gid < 1024) {
        int t = gid; // k*64+h
        float rs1 = rsqrtf(ev1[t] + EPS) * eg1[t];
        wsf[OFF_SC1 + t] = rs1;
        wsf[OFF_SH1 + t] = fmaf(eb1[t] - em1[t], rs1, ebe1[t]);
        float rs2 = rsqrtf(ev2[t] + EPS) * eg2[t];
        wsf[OFF_SC2 + t] = rs2;
        wsf[OFF_SH2 + t] = fmaf(eb2[t] - em2[t], rs2, ebe2[t]);
    } else if (gid < 1024 + 64) {
        int t = gid - 1024;
        float rs = rsqrtf(pv[t] + EPS) * pg[t];
        wsf[OFF_SCP + t] = rs;
        wsf[OFF_SHP + t] = fmaf(pb1[t] - pm[t], rs, pbe[t]);
    } else if (gid < 1024 + 64 + 16) {
        gcnt[gid - (1024 + 64)] = 0;
    }
}

// ---------------- gate: sliced MLP (scalar weights) + softmax + top2 + list build ----------------
__global__ __launch_bounds__(256, 2) void k_gate(
    const int* __restrict__ sql, const float* __restrict__ sql_table,
    const float* __restrict__ gw1, const float* __restrict__ gb1,
    const float* __restrict__ gw2, const float* __restrict__ gb2,
    int* __restrict__ lidx, float* __restrict__ lw,
    int* __restrict__ gcnt, float* __restrict__ imp_part)
{
    __shared__ float exch[4 * KEXP * 65];   // 16640 B, [wave][j][65]
    __shared__ float s_imp[KEXP];
    __shared__ int s_cnt[KEXP];
    __shared__ int s_base[KEXP];
    int tid = threadIdx.x;
    int wid = tid >> 6, lane = tid & 63;
    int hb = __builtin_amdgcn_readfirstlane(wid * 16);
    const float* W1 = gw1 + hb;           // wave-uniform base -> s_load
    if (tid < KEXP) s_imp[tid] = 0.f;
    __syncthreads();

    for (int c = blockIdx.x; c < NCHUNK; c += gridDim.x) {
        int b = c * 64 + lane;
        int si[NFIELD];
#pragma unroll
        for (int j = 0; j < NFIELD / 4; ++j) {
            int4 t = *(const int4*)(sql + (size_t)b * NFIELD + 4 * j);
            si[4 * j] = t.x; si[4 * j + 1] = t.y; si[4 * j + 2] = t.z; si[4 * j + 3] = t.w;
        }
        float xv[SQL_NEMB], xn[SQL_NEMB];
#pragma unroll
        for (int j = 0; j < SQL_NEMB / 2; ++j) {
            float2 t = *(const float2*)(sql_table + (size_t)si[0] * SQL_NEMB + 2 * j);
            xv[2 * j] = t.x; xv[2 * j + 1] = t.y;
        }
        float acc[16];
#pragma unroll
        for (int h = 0; h < 16; ++h) acc[h] = 0.f;
        for (int f = 0; f < NFIELD; f += 2) {
#pragma unroll
            for (int j = 0; j < SQL_NEMB / 2; ++j) {
                float2 t = *(const float2*)(sql_table + (size_t)si[f + 1] * SQL_NEMB + 2 * j);
                xn[2 * j] = t.x; xn[2 * j + 1] = t.y;
            }
#pragma unroll
            for (int i = 0; i < SQL_NEMB; ++i) {
                const float* wr = &W1[(f * SQL_NEMB + i) * HID];
#pragma unroll
                for (int h = 0; h < 16; ++h) acc[h] = fmaf(xv[i], wr[h], acc[h]);
            }
            if (f + 2 < NFIELD) {
#pragma unroll
                for (int j = 0; j < SQL_NEMB / 2; ++j) {
                    float2 t = *(const float2*)(sql_table + (size_t)si[f + 2] * SQL_NEMB + 2 * j);
                    xv[2 * j] = t.x; xv[2 * j + 1] = t.y;
                }
            }
#pragma unroll
            for (int i = 0; i < SQL_NEMB; ++i) {
                const float* wr = &W1[((f + 1) * SQL_NEMB + i) * HID];
#pragma unroll
                for (int h = 0; h < 16; ++h) acc[h] = fmaf(xn[i], wr[h], acc[h]);
            }
        }
        // partial logits over this wave's 16 hidden units
        float pz[KEXP];
#pragma unroll
        for (int j = 0; j < KEXP; ++j) pz[j] = 0.f;
#pragma unroll
        for (int hh = 0; hh < 16; ++hh) {
            float g = fmaxf(acc[hh] + gb1[hb + hh], 0.f);
            const float* wr = gw2 + (hb + hh) * KEXP;
#pragma unroll
            for (int j = 0; j < KEXP; ++j) pz[j] = fmaf(g, wr[j], pz[j]);
        }
#pragma unroll
        for (int j = 0; j < KEXP; ++j)
            exch[(wid * KEXP + j) * 65 + lane] = pz[j];
        __syncthreads();

        if (wid == 0) {
            float z[KEXP];
#pragma unroll
            for (int j = 0; j < KEXP; ++j)
                z[j] = gb2[j] + exch[j * 65 + lane]
                     + exch[(KEXP + j) * 65 + lane]
                     + exch[(2 * KEXP + j) * 65 + lane]
                     + exch[(3 * KEXP + j) * 65 + lane];
            float m = z[0];
#pragma unroll
            for (int j = 1; j < KEXP; ++j) m = fmaxf(m, z[j]);
            float s = 0.f;
#pragma unroll
            for (int j = 0; j < KEXP; ++j) s += expf(z[j] - m);
            int i0 = 0; float m0 = z[0];
#pragma unroll
            for (int j = 1; j < KEXP; ++j) if (z[j] > m0) { m0 = z[j]; i0 = j; }
            int i1 = (i0 == 0) ? 1 : 0; float m1 = -3.4e38f;
#pragma unroll
            for (int j = 0; j < KEXP; ++j) if (j != i0 && z[j] > m1) { m1 = z[j]; i1 = j; }
            float v0 = expf(m0 - m) / s, v1 = expf(m1 - m) / s;
            float inv = 1.f / (v0 + v1 + 1e-9f);
            float w0 = v0 * inv, w1 = v1 * inv;

            if (lane < KEXP) s_cnt[lane] = 0;
            atomicAdd(&s_imp[i0], w0);
            atomicAdd(&s_imp[i1], w1);
            int o0 = atomicAdd(&s_cnt[i0], 1);
            int o1 = atomicAdd(&s_cnt[i1], 1);
            if (lane < KEXP) s_base[lane] = atomicAdd(&gcnt[lane], s_cnt[lane]);
            int p0 = i0 * BB + s_base[i0] + o0;
            lidx[p0] = (b << 1);     lw[p0] = w0;
            int p1 = i1 * BB + s_base[i1] + o1;
            lidx[p1] = (b << 1) | 1; lw[p1] = w1;
        }
        __syncthreads();
    }
    if (tid < KEXP) imp_part[blockIdx.x * KEXP + tid] = s_imp[tid];
}

// ---------------- loss from importance partials ----------------
__global__ __launch_bounds__(256) void k_loss(const float* __restrict__ imp_part,
                                              float* __restrict__ out)
{
    __shared__ double sred[16][17];
    __shared__ double simp[KEXP];
    int tid = threadIdx.x;
    int j = tid & 15, g = tid >> 4;
    double s = 0.0;
    for (int blk = g; blk < NBLK_GATE; blk += 16) s += (double)imp_part[blk * KEXP + j];
    sred[g][j] = s;
    __syncthreads();
    if (tid < KEXP) {
        double t = 0.0;
#pragma unroll
        for (int gg = 0; gg < 16; ++gg) t += sred[gg][tid];
        simp[tid] = t;
    }
    __syncthreads();
    if (tid == 0) {
        double mean = 0.0;
        for (int jj = 0; jj < KEXP; ++jj) mean += simp[jj];
        mean /= KEXP;
        double var = 0.0;
        for (int jj = 0; jj < KEXP; ++jj) { double d = simp[jj] - mean; var += d * d; }
        var /= KEXP;
        out[BB] = (float)(var / (mean * mean + 1e-10));
    }
}

// ---------------- expert layer 1 (sliced, scalar weights): emb @ W1 + BN/ReLU -> h1 ----------------
__global__ __launch_bounds__(256, 2) void k_exp1(
    const int* __restrict__ x, const float* __restrict__ itab,
    const float* __restrict__ ew1,
    const float* __restrict__ sc1, const float* __restrict__ sh1,
    const int* __restrict__ lidx, const int* __restrict__ gcnt,
    float* __restrict__ h1buf)
{
    int k = blockIdx.y;
    int tid = threadIdx.x;
    int lane = tid & 63;
    int hb = __builtin_amdgcn_readfirstlane((tid >> 6) * 16);
    const float* W1  = ew1 + (size_t)k * (EXP_IN * HID) + hb;  // wave-uniform -> s_load
    const float* scb = sc1 + k * HID + hb;
    const float* shb = sh1 + k * HID + hb;
    int n = gcnt[k];
    for (int base = blockIdx.x * 64; base < n; base += gridDim.x * 64) {
        int it = base + lane;
        if (it >= n) continue;
        int e = lidx[k * BB + it];
        int b = e >> 1;

        int xi[NFIELD];
#pragma unroll
        for (int j = 0; j < NFIELD / 4; ++j) {
            int4 t = *(const int4*)(x + (size_t)b * NFIELD + 4 * j);
            xi[4 * j] = t.x; xi[4 * j + 1] = t.y; xi[4 * j + 2] = t.z; xi[4 * j + 3] = t.w;
        }
        float xv[DATA_NEMB], xn[DATA_NEMB];
#pragma unroll
        for (int j = 0; j < DATA_NEMB / 2; ++j) {
            float2 t = *(const float2*)(itab + (size_t)xi[0] * DATA_NEMB + 2 * j);
            xv[2 * j] = t.x; xv[2 * j + 1] = t.y;
        }
        float acc[16];
#pragma unroll
        for (int h = 0; h < 16; ++h) acc[h] = 0.f;
        for (int f = 0; f < NFIELD; f += 2) {
#pragma unroll
            for (int j = 0; j < DATA_NEMB / 2; ++j) {
                float2 t = *(const float2*)(itab + (size_t)xi[f + 1] * DATA_NEMB + 2 * j);
                xn[2 * j] = t.x; xn[2 * j + 1] = t.y;
            }
#pragma unroll
            for (int i = 0; i < DATA_NEMB; ++i) {
                const float* wr = &W1[(f * DATA_NEMB + i) * HID];
#pragma unroll
                for (int h = 0; h < 16; ++h) acc[h] = fmaf(xv[i], wr[h], acc[h]);
            }
            if (f + 2 < NFIELD) {
#pragma unroll
                for (int j = 0; j < DATA_NEMB / 2; ++j) {
                    float2 t = *(const float2*)(itab + (size_t)xi[f + 2] * DATA_NEMB + 2 * j);
                    xv[2 * j] = t.x; xv[2 * j + 1] = t.y;
                }
            }
#pragma unroll
            for (int i = 0; i < DATA_NEMB; ++i) {
                const float* wr = &W1[((f + 1) * DATA_NEMB + i) * HID];
#pragma unroll
                for (int h = 0; h < 16; ++h) acc[h] = fmaf(xn[i], wr[h], acc[h]);
            }
        }
        float* outp = h1buf + (size_t)e * HID + hb;
#pragma unroll
        for (int q = 0; q < 4; ++q) {
            float4 v;
            v.x = fmaxf(fmaf(acc[4 * q + 0], scb[4 * q + 0], shb[4 * q + 0]), 0.f);
            v.y = fmaxf(fmaf(acc[4 * q + 1], scb[4 * q + 1], shb[4 * q + 1]), 0.f);
            v.z = fmaxf(fmaf(acc[4 * q + 2], scb[4 * q + 2], shb[4 * q + 2]), 0.f);
            v.w = fmaxf(fmaf(acc[4 * q + 3], scb[4 * q + 3], shb[4 * q + 3]), 0.f);
            *(float4*)(outp + 4 * q) = v;
        }
    }
}

// ---------------- expert layer 2 (sliced, scalar weights): h1 @ W2 + BN/ReLU, * gate -> hs ----------------
__global__ __launch_bounds__(256, 2) void k_exp2(
    const float* __restrict__ ew2,
    const float* __restrict__ sc2, const float* __restrict__ sh2,
    const int* __restrict__ lidx, const float* __restrict__ lw,
    const int* __restrict__ gcnt,
    const float* __restrict__ h1buf, float* __restrict__ hs)
{
    int k = blockIdx.y;
    int tid = threadIdx.x;
    int lane = tid & 63;
    int gb = __builtin_amdgcn_readfirstlane((tid >> 6) * 16);
    const float* W2  = ew2 + (size_t)k * (HID * HID) + gb;  // [i][g] layout, uniform base
    const float* scb = sc2 + k * HID + gb;
    const float* shb = sh2 + k * HID + gb;
    int n = gcnt[k];
    for (int base = blockIdx.x * 64; base < n; base += gridDim.x * 64) {
        int it = base + lane;
        if (it >= n) continue;
        int e = lidx[k * BB + it];
        float w = lw[k * BB + it];
        const float* hp = h1buf + (size_t)e * HID;
        float4 hv = *(const float4*)(hp);
        float acc[16];
#pragma unroll
        for (int g = 0; g < 16; ++g) acc[g] = 0.f;
#pragma unroll
        for (int i0 = 0; i0 < 16; ++i0) {
            float4 cur = hv;
            if (i0 < 15) hv = *(const float4*)(hp + 4 * (i0 + 1));
            float hvv[4] = {cur.x, cur.y, cur.z, cur.w};
#pragma unroll
            for (int u = 0; u < 4; ++u) {
                const float* wr = &W2[(4 * i0 + u) * HID];
#pragma unroll
                for (int g = 0; g < 16; ++g) acc[g] = fmaf(hvv[u], wr[g], acc[g]);
            }
        }
        float* outp = hs + (size_t)e * HID + gb;
#pragma unroll
        for (int q = 0; q < 4; ++q) {
            float4 v;
            v.x = w * fmaxf(fmaf(acc[4 * q + 0], scb[4 * q + 0], shb[4 * q + 0]), 0.f);
            v.y = w * fmaxf(fmaf(acc[4 * q + 1], scb[4 * q + 1], shb[4 * q + 1]), 0.f);
            v.z = w * fmaxf(fmaf(acc[4 * q + 2], scb[4 * q + 2], shb[4 * q + 2]), 0.f);
            v.w = w * fmaxf(fmaf(acc[4 * q + 3], scb[4 * q + 3], shb[4 * q + 3]), 0.f);
            *(float4*)(outp + 4 * q) = v;
        }
    }
}

// ---------------- predict head (sliced, scalar weights) ----------------
__global__ __launch_bounds__(256, 2) void k_head(
    const float* __restrict__ hs, const float* __restrict__ pw1,
    const float* __restrict__ scp, const float* __restrict__ shp,
    const float* __restrict__ pw2, const float* __restrict__ pb2,
    float* __restrict__ out)
{
    __shared__ float pex[4][64];
    int tid = threadIdx.x;
    int wid = tid >> 6, lane = tid & 63;
    int gb = __builtin_amdgcn_readfirstlane(wid * 16);
    const float* PW = pw1 + gb;  // [i][g] layout, uniform base

    for (int c = blockIdx.x; c < NCHUNK; c += gridDim.x) {
        int b = c * 64 + lane;
        const float* hp = hs + (size_t)b * 128;
        float acc[16];
#pragma unroll
        for (int g = 0; g < 16; ++g) acc[g] = 0.f;
#pragma unroll
        for (int i0 = 0; i0 < 16; ++i0) {
            float4 a = *(const float4*)(hp + 4 * i0);
            float4 d = *(const float4*)(hp + 64 + 4 * i0);
            float y4[4] = {a.x + d.x, a.y + d.y, a.z + d.z, a.w + d.w};
#pragma unroll
            for (int u = 0; u < 4; ++u) {
                const float* wr = &PW[(4 * i0 + u) * HID];
#pragma unroll
                for (int g = 0; g < 16; ++g) acc[g] = fmaf(y4[u], wr[g], acc[g]);
            }
        }
        float po = 0.f;
#pragma unroll
        for (int g = 0; g < 16; ++g) {
            float ph = fmaxf(fmaf(acc[g], scp[gb + g], shp[gb + g]), 0.f);
            po = fmaf(ph, pw2[gb + g], po);
        }
        pex[wid][lane] = po;
        __syncthreads();
        if (wid == 0)
            out[b] = pb2[0] + pex[0][lane] + pex[1][lane] + pex[2][lane] + pex[3][lane];
        __syncthreads();
    }
}

extern "C" void kernel_launch(void* const* d_in, const int* in_sizes, int n_in,
                              void* d_out, int out_size, void* d_ws, size_t ws_size,
                              hipStream_t stream) {
    const int*   x     = (const int*)d_in[0];
    const int*   sql   = (const int*)d_in[1];
    const float* itab  = (const float*)d_in[2];
    const float* stab  = (const float*)d_in[3];
    const float* gw1   = (const float*)d_in[4];
    const float* gb1   = (const float*)d_in[5];
    const float* gw2   = (const float*)d_in[6];
    const float* gb2   = (const float*)d_in[7];
    const float* ew1   = (const float*)d_in[8];
    const float* eb1   = (const float*)d_in[9];
    const float* eg1   = (const float*)d_in[10];
    const float* ebe1  = (const float*)d_in[11];
    const float* em1   = (const float*)d_in[12];
    const float* ev1   = (const float*)d_in[13];
    const float* ew2   = (const float*)d_in[14];
    const float* eb2   = (const float*)d_in[15];
    const float* eg2   = (const float*)d_in[16];
    const float* ebe2  = (const float*)d_in[17];
    const float* em2   = (const float*)d_in[18];
    const float* ev2   = (const float*)d_in[19];
    const float* pw1   = (const float*)d_in[20];
    const float* pb1   = (const float*)d_in[21];
    const float* pg    = (const float*)d_in[22];
    const float* pbe   = (const float*)d_in[23];
    const float* pm    = (const float*)d_in[24];
    const float* pv    = (const float*)d_in[25];
    const float* pw2   = (const float*)d_in[26];
    const float* pb2   = (const float*)d_in[27];

    float* wsf  = (float*)d_ws;
    int*   wsi  = (int*)d_ws;
    int*   gcnt = wsi + OFF_GCNT;
    float* sc1  = wsf + OFF_SC1;
    float* sh1  = wsf + OFF_SH1;
    float* sc2  = wsf + OFF_SC2;
    float* sh2  = wsf + OFF_SH2;
    float* scp  = wsf + OFF_SCP;
    float* shp  = wsf + OFF_SHP;
    float* imp  = wsf + OFF_IMP;
    int*   lidx = wsi + OFF_LIDX;
    float* lw   = wsf + OFF_LW;
    float* hs   = wsf + OFF_HS;
    float* h1b  = wsf + OFF_H1;
    float* out  = (float*)d_out;

    k_prep<<<5, 256, 0, stream>>>(eb1, eg1, ebe1, em1, ev1,
                                  eb2, eg2, ebe2, em2, ev2,
                                  pb1, pg, pbe, pm, pv, wsf, gcnt);
    k_gate<<<NBLK_GATE, 256, 0, stream>>>(sql, stab, gw1, gb1, gw2, gb2,
                                          lidx, lw, gcnt, imp);
    k_loss<<<1, 256, 0, stream>>>(imp, out);
    dim3 g1(64, KEXP);
    k_exp1<<<g1, 256, 0, stream>>>(x, itab, ew1, sc1, sh1, lidx, gcnt, h1b);
    dim3 g2(64, KEXP);
    k_exp2<<<g2, 256, 0, stream>>>(ew2, sc2, sh2, lidx, lw, gcnt, h1b, hs);
    k_head<<<1024, 256, 0, stream>>>(hs, pw1, scp, shp, pw2, pb2, out);
}

// Round 5
// 154.008 us; speedup vs baseline: 2.2001x; 2.2001x over previous
//
#include <hip/hip_runtime.h>
#include <hip/hip_bf16.h>

#define BB 65536
#define NFIELD 20
#define HID 64
#define KEXP 16
#define EPS 1e-5f
#define KPAD 224
#define NKS 7            // 224/32 K-steps
#define NBLK_GATE 256
#define NBX_EXP 40

typedef __attribute__((ext_vector_type(8))) short v8s;   // 8 bf16
typedef __attribute__((ext_vector_type(4))) float v4f;

// ---- ws layout (4B element offsets) ----
#define OFF_GCNT 0
#define OFF_SC1 64
#define OFF_SH1 1088
#define OFF_SC2 2112
#define OFF_SH2 3136
#define OFF_SCP 4160
#define OFF_SHP 4224
#define OFF_IMP 4288            // 256*16
#define OFF_LIDX 8448           // 16*BB int
#define OFF_LW  1057024         // 16*BB f32
#define OFF_W1T 2105600         // 16*64*224 bf16
#define OFF_GW1T 2220288        // 64*224 bf16
#define OFF_W2T 2227456         // 16*64*64 bf16
#define OFF_PW1T 2260224        // 64*64 bf16
#define OFF_XEMB 2262272        // 65537*224 bf16
#define OFF_SQEMB 9602416       // 65536*224 bf16
#define OFF_HS 16942448         // 131073*64 bf16

__device__ __forceinline__ unsigned short f2bf(float f) {
    unsigned int u = __float_as_uint(f);
    unsigned int r = (u + 0x7FFFu + ((u >> 16) & 1u)) >> 16;
    return (unsigned short)r;
}
__device__ __forceinline__ float bf2f(unsigned short u) {
    unsigned int t = ((unsigned int)u) << 16;
    return __uint_as_float(t);
}

// ---------------- prep: BN folds + bf16 weight transposes + gcnt zero ----------------
__global__ __launch_bounds__(256) void k_prep(
    const float* __restrict__ ew1, const float* __restrict__ ew2,
    const float* __restrict__ gw1, const float* __restrict__ pw1,
    const float* __restrict__ eb1, const float* __restrict__ eg1,
    const float* __restrict__ ebe1, const float* __restrict__ em1,
    const float* __restrict__ ev1,
    const float* __restrict__ eb2, const float* __restrict__ eg2,
    const float* __restrict__ ebe2, const float* __restrict__ em2,
    const float* __restrict__ ev2,
    const float* __restrict__ pb1, const float* __restrict__ pg,
    const float* __restrict__ pbe, const float* __restrict__ pm,
    const float* __restrict__ pv,
    float* __restrict__ wsf, int* __restrict__ gcnt,
    unsigned short* __restrict__ w1t, unsigned short* __restrict__ gw1t,
    unsigned short* __restrict__ w2t, unsigned short* __restrict__ pw1t)
{
    int gid = blockIdx.x * 256 + threadIdx.x;
    if (gid < 229376) {               // W1T[k][c][t] = ew1[k][t][c]
        int k = gid / 14336, r = gid % 14336, c = r / KPAD, t = r % KPAD;
        w1t[gid] = (t < 200) ? f2bf(ew1[((size_t)k * 200 + t) * HID + c]) : 0;
    } else if (gid < 229376 + 14336) { // gw1T[c][t]
        int g2 = gid - 229376; int c = g2 / KPAD, t = g2 % KPAD;
        gw1t[g2] = (t < 200) ? f2bf(gw1[t * HID + c]) : 0;
    } else if (gid < 243712 + 65536) { // W2T[k][g][i] = ew2[k][i][g]
        int g2 = gid - 243712; int k = g2 / 4096, r = g2 % 4096, g = r / 64, i = r % 64;
        w2t[g2] = f2bf(ew2[((size_t)k * 64 + i) * 64 + g]);
    } else if (gid < 309248 + 4096) {  // PW1T[g][i] = pw1[i][g]
        int g2 = gid - 309248; int g = g2 / 64, i = g2 % 64;
        pw1t[g2] = f2bf(pw1[i * 64 + g]);
    } else if (gid < 313344 + 1024) {
        int t = gid - 313344;
        float rs1 = rsqrtf(ev1[t] + EPS) * eg1[t];
        wsf[OFF_SC1 + t] = rs1;
        wsf[OFF_SH1 + t] = fmaf(eb1[t] - em1[t], rs1, ebe1[t]);
        float rs2 = rsqrtf(ev2[t] + EPS) * eg2[t];
        wsf[OFF_SC2 + t] = rs2;
        wsf[OFF_SH2 + t] = fmaf(eb2[t] - em2[t], rs2, ebe2[t]);
    } else if (gid < 314368 + 64) {
        int t = gid - 314368;
        float rs = rsqrtf(pv[t] + EPS) * pg[t];
        wsf[OFF_SCP + t] = rs;
        wsf[OFF_SHP + t] = fmaf(pb1[t] - pm[t], rs, pbe[t]);
    } else if (gid < 314432 + 16) {
        gcnt[gid - 314432] = 0;
    }
}

// ---------------- gathers -> bf16 padded embedding matrices ----------------
__global__ __launch_bounds__(256) void k_emb(
    const int* __restrict__ x, const int* __restrict__ sql,
    const float* __restrict__ itab, const float* __restrict__ stab,
    unsigned short* __restrict__ xembT, unsigned short* __restrict__ sqembT)
{
    int gid = blockIdx.x * 256 + threadIdx.x;
    const int half = 65536 * 112;
    int sel = gid >= half;
    int g2 = sel ? gid - half : gid;
    int b = g2 / 112, p = g2 % 112;           // p = pair index, col = 2p
    unsigned short* dst = sel ? sqembT : xembT;
    unsigned int pack = 0;
    if (p < 100) {
        int f = p / 5;                        // field
        int j = 2 * (p % 5);                  // offset within field
        int idx = (sel ? sql : x)[b * NFIELD + f];
        const float* row = (sel ? stab : itab) + (size_t)idx * 10 + j;
        float2 t = *(const float2*)row;
        pack = (unsigned int)f2bf(t.x) | ((unsigned int)f2bf(t.y) << 16);
    }
    *(unsigned int*)(dst + (size_t)b * KPAD + 2 * p) = pack;
}

// ---------------- gate: MFMA L1 + per-lane logits/softmax/top2 + list build ----------------
__global__ __launch_bounds__(256, 2) void k_gate(
    const unsigned short* __restrict__ sqembT, const unsigned short* __restrict__ gw1t,
    const float* __restrict__ gb1, const float* __restrict__ gw2,
    const float* __restrict__ gb2,
    int* __restrict__ lidx, float* __restrict__ lw,
    int* __restrict__ gcnt, float* __restrict__ imp_part)
{
    __shared__ unsigned short Hg[4][64][80];
    __shared__ float s_imp[KEXP];
    __shared__ int s_cnt[KEXP];
    __shared__ int s_base[KEXP];
    int tid = threadIdx.x;
    int wid = tid >> 6, l = tid & 63;
    int m = l & 15, q = l >> 4;
    if (tid < KEXP) { s_imp[tid] = 0.f; s_cnt[tid] = 0; }
    __syncthreads();

    int it0 = blockIdx.x * 256 + wid * 64;
    v4f zero4 = {0.f, 0.f, 0.f, 0.f};
    v4f acc[4][4];
#pragma unroll
    for (int a = 0; a < 4; ++a)
#pragma unroll
        for (int c = 0; c < 4; ++c) acc[a][c] = zero4;

    const unsigned short* Ab = sqembT + (size_t)it0 * KPAD + q * 8;
    const unsigned short* Bb = gw1t + m * KPAD + q * 8;
#pragma unroll
    for (int Ks = 0; Ks < NKS; ++Ks) {
        v8s a[4], b[4];
#pragma unroll
        for (int Mt = 0; Mt < 4; ++Mt)
            a[Mt] = *(const v8s*)(Ab + (Mt * 16 + m) * KPAD + Ks * 32);
#pragma unroll
        for (int Nt = 0; Nt < 4; ++Nt)
            b[Nt] = *(const v8s*)(Bb + Nt * 16 * KPAD + Ks * 32);
#pragma unroll
        for (int Mt = 0; Mt < 4; ++Mt)
#pragma unroll
            for (int Nt = 0; Nt < 4; ++Nt)
                acc[Mt][Nt] = __builtin_amdgcn_mfma_f32_16x16x32_bf16(a[Mt], b[Nt], acc[Mt][Nt], 0, 0, 0);
    }
    // bias + relu -> swizzled LDS (bf16)
#pragma unroll
    for (int Nt = 0; Nt < 4; ++Nt) {
        int c = Nt * 16 + m;
        float bias = gb1[c];
#pragma unroll
        for (int Mt = 0; Mt < 4; ++Mt)
#pragma unroll
            for (int j = 0; j < 4; ++j) {
                int item = Mt * 16 + q * 4 + j;
                float v = fmaxf(acc[Mt][Nt][j] + bias, 0.f);
                Hg[wid][item][c ^ ((item & 7) << 3)] = f2bf(v);
            }
    }
    // per-lane: logits for item = it0 + l
    float z[KEXP];
#pragma unroll
    for (int j = 0; j < KEXP; ++j) z[j] = gb2[j];
#pragma unroll
    for (int u = 0; u < 8; ++u) {
        v8s hv = *(const v8s*)&Hg[wid][l][(u * 8) ^ ((l & 7) << 3)];
#pragma unroll
        for (int e = 0; e < 8; ++e) {
            int h = u * 8 + e;
            float g = bf2f((unsigned short)hv[e]);
#pragma unroll
            for (int j = 0; j < KEXP; ++j) z[j] = fmaf(g, gw2[h * KEXP + j], z[j]);
        }
    }
    float mm = z[0];
#pragma unroll
    for (int j = 1; j < KEXP; ++j) mm = fmaxf(mm, z[j]);
    float s = 0.f;
#pragma unroll
    for (int j = 0; j < KEXP; ++j) s += expf(z[j] - mm);
    int i0 = 0; float m0 = z[0];
#pragma unroll
    for (int j = 1; j < KEXP; ++j) if (z[j] > m0) { m0 = z[j]; i0 = j; }
    int i1 = (i0 == 0) ? 1 : 0; float m1 = -3.4e38f;
#pragma unroll
    for (int j = 0; j < KEXP; ++j) if (j != i0 && z[j] > m1) { m1 = z[j]; i1 = j; }
    float v0 = expf(m0 - mm) / s, v1 = expf(m1 - mm) / s;
    float inv = 1.f / (v0 + v1 + 1e-9f);
    float w0 = v0 * inv, w1 = v1 * inv;

    int b = blockIdx.x * 256 + tid;
    atomicAdd(&s_imp[i0], w0);
    atomicAdd(&s_imp[i1], w1);
    int o0 = atomicAdd(&s_cnt[i0], 1);
    int o1 = atomicAdd(&s_cnt[i1], 1);
    __syncthreads();
    if (tid < KEXP) {
        imp_part[blockIdx.x * KEXP + tid] = s_imp[tid];
        s_base[tid] = atomicAdd(&gcnt[tid], s_cnt[tid]);
    }
    __syncthreads();
    int p0 = i0 * BB + s_base[i0] + o0;
    lidx[p0] = (b << 1);     lw[p0] = w0;
    int p1 = i1 * BB + s_base[i1] + o1;
    lidx[p1] = (b << 1) | 1; lw[p1] = w1;
}

// ---------------- pad each expert list to multiple of 64 with benign entries ----------------
__global__ void k_pad(const int* __restrict__ gcnt, int* __restrict__ lidx,
                      float* __restrict__ lw)
{
    int k = blockIdx.x;
    int n = gcnt[k];
    int ne = (n + 63) & ~63;
    for (int i = n + threadIdx.x; i < ne; i += 64) {
        lidx[k * BB + i] = 2 * BB;   // dedicated pad row
        lw[k * BB + i] = 0.f;
    }
}

// ---------------- loss ----------------
__global__ __launch_bounds__(256) void k_loss(const float* __restrict__ imp_part,
                                              float* __restrict__ out)
{
    __shared__ double sred[16][17];
    __shared__ double simp[KEXP];
    int tid = threadIdx.x;
    int j = tid & 15, g = tid >> 4;
    double s = 0.0;
    for (int blk = g; blk < NBLK_GATE; blk += 16) s += (double)imp_part[blk * KEXP + j];
    sred[g][j] = s;
    __syncthreads();
    if (tid < KEXP) {
        double t = 0.0;
#pragma unroll
        for (int gg = 0; gg < 16; ++gg) t += sred[gg][tid];
        simp[tid] = t;
    }
    __syncthreads();
    if (tid == 0) {
        double mean = 0.0;
        for (int jj = 0; jj < KEXP; ++jj) mean += simp[jj];
        mean /= KEXP;
        double var = 0.0;
        for (int jj = 0; jj < KEXP; ++jj) { double d = simp[jj] - mean; var += d * d; }
        var /= KEXP;
        out[BB] = (float)(var / (mean * mean + 1e-10));
    }
}

// ---------------- fused expert: MFMA L1 -> LDS -> MFMA L2 -> hs (bf16) ----------------
__global__ __launch_bounds__(256, 2) void k_exp(
    const unsigned short* __restrict__ xembT,
    const unsigned short* __restrict__ w1t, const unsigned short* __restrict__ w2t,
    const float* __restrict__ sc1, const float* __restrict__ sh1,
    const float* __restrict__ sc2, const float* __restrict__ sh2,
    const int* __restrict__ lidx, const float* __restrict__ lw,
    const int* __restrict__ gcnt, unsigned short* __restrict__ hs)
{
    __shared__ unsigned short Hl[4][64][80];
    int k = blockIdx.y;
    int tid = threadIdx.x;
    int wid = tid >> 6, l = tid & 63;
    int m = l & 15, q = l >> 4;
    int n = gcnt[k];
    int ne = (n + 63) & ~63;
    const unsigned short* W1 = w1t + (size_t)k * 64 * KPAD + m * KPAD + q * 8;
    const unsigned short* W2 = w2t + (size_t)k * 64 * 64 + m * 64 + q * 8;
    float sc1v[4], sh1v[4], sc2v[4], sh2v[4];
#pragma unroll
    for (int Nt = 0; Nt < 4; ++Nt) {
        int c = Nt * 16 + m;
        sc1v[Nt] = sc1[k * HID + c]; sh1v[Nt] = sh1[k * HID + c];
        sc2v[Nt] = sc2[k * HID + c]; sh2v[Nt] = sh2[k * HID + c];
    }
    v4f zero4 = {0.f, 0.f, 0.f, 0.f};

    for (int it0 = (blockIdx.x * 4 + wid) * 64; it0 < ne; it0 += NBX_EXP * 256) {
        // ---- layer 1 ----
        int eA[4];
#pragma unroll
        for (int Mt = 0; Mt < 4; ++Mt) eA[Mt] = lidx[k * BB + it0 + Mt * 16 + m];
        v4f acc1[4][4];
#pragma unroll
        for (int a = 0; a < 4; ++a)
#pragma unroll
            for (int c = 0; c < 4; ++c) acc1[a][c] = zero4;
#pragma unroll
        for (int Ks = 0; Ks < NKS; ++Ks) {
            v8s a[4], b[4];
#pragma unroll
            for (int Mt = 0; Mt < 4; ++Mt)
                a[Mt] = *(const v8s*)(xembT + (size_t)(eA[Mt] >> 1) * KPAD + Ks * 32 + q * 8);
#pragma unroll
            for (int Nt = 0; Nt < 4; ++Nt)
                b[Nt] = *(const v8s*)(W1 + Nt * 16 * KPAD + Ks * 32);
#pragma unroll
            for (int Mt = 0; Mt < 4; ++Mt)
#pragma unroll
                for (int Nt = 0; Nt < 4; ++Nt)
                    acc1[Mt][Nt] = __builtin_amdgcn_mfma_f32_16x16x32_bf16(a[Mt], b[Nt], acc1[Mt][Nt], 0, 0, 0);
        }
        // BN1 + relu -> swizzled LDS
#pragma unroll
        for (int Nt = 0; Nt < 4; ++Nt) {
            int c = Nt * 16 + m;
#pragma unroll
            for (int Mt = 0; Mt < 4; ++Mt)
#pragma unroll
                for (int j = 0; j < 4; ++j) {
                    int item = Mt * 16 + q * 4 + j;
                    float v = fmaxf(fmaf(acc1[Mt][Nt][j], sc1v[Nt], sh1v[Nt]), 0.f);
                    Hl[wid][item][c ^ ((item & 7) << 3)] = f2bf(v);
                }
        }
        // ---- layer 2 (K=64) ----
        v4f acc2[4][4];
#pragma unroll
        for (int a = 0; a < 4; ++a)
#pragma unroll
            for (int c = 0; c < 4; ++c) acc2[a][c] = zero4;
#pragma unroll
        for (int Ks = 0; Ks < 2; ++Ks) {
            v8s a[4], b[4];
#pragma unroll
            for (int Mt = 0; Mt < 4; ++Mt)
                a[Mt] = *(const v8s*)&Hl[wid][Mt * 16 + m][(Ks * 32 + q * 8) ^ ((m & 7) << 3)];
#pragma unroll
            for (int Nt = 0; Nt < 4; ++Nt)
                b[Nt] = *(const v8s*)(W2 + Nt * 16 * 64 + Ks * 32);
#pragma unroll
            for (int Mt = 0; Mt < 4; ++Mt)
#pragma unroll
                for (int Nt = 0; Nt < 4; ++Nt)
                    acc2[Mt][Nt] = __builtin_amdgcn_mfma_f32_16x16x32_bf16(a[Mt], b[Nt], acc2[Mt][Nt], 0, 0, 0);
        }
        // BN2 + relu, * gate weight -> swizzled LDS (reuse)
#pragma unroll
        for (int Mt = 0; Mt < 4; ++Mt) {
            int4 eC = *(const int4*)&lidx[k * BB + it0 + Mt * 16 + q * 4];
            float4 wC = *(const float4*)&lw[k * BB + it0 + Mt * 16 + q * 4];
            float wj[4] = {wC.x, wC.y, wC.z, wC.w};
            (void)eC;
#pragma unroll
            for (int Nt = 0; Nt < 4; ++Nt) {
                int c = Nt * 16 + m;
#pragma unroll
                for (int j = 0; j < 4; ++j) {
                    int item = Mt * 16 + q * 4 + j;
                    float v = wj[j] * fmaxf(fmaf(acc2[Mt][Nt][j], sc2v[Nt], sh2v[Nt]), 0.f);
                    Hl[wid][item][c ^ ((item & 7) << 3)] = f2bf(v);
                }
            }
        }
        // per-lane: write own row to hs[e][64] (coalesced 16B chunks)
        int eo = lidx[k * BB + it0 + l];
        unsigned short* hrow = hs + (size_t)eo * HID;
#pragma unroll
        for (int u = 0; u < 8; ++u)
            *(v8s*)(hrow + u * 8) = *(const v8s*)&Hl[wid][l][(u * 8) ^ ((l & 7) << 3)];
    }
}

// ---------------- head: sum slots + MFMA (K=64) + BN/relu + dot pw2 ----------------
__global__ __launch_bounds__(256, 2) void k_head(
    const unsigned short* __restrict__ hs, const unsigned short* __restrict__ pw1t,
    const float* __restrict__ scp, const float* __restrict__ shp,
    const float* __restrict__ pw2, const float* __restrict__ pb2,
    float* __restrict__ out)
{
    int tid = threadIdx.x;
    int wid = tid >> 6, l = tid & 63;
    int m = l & 15, q = l >> 4;
    int it0 = blockIdx.x * 256 + wid * 64;
    float scv[4], shv[4], w2v[4];
#pragma unroll
    for (int Nt = 0; Nt < 4; ++Nt) {
        int c = Nt * 16 + m;
        scv[Nt] = scp[c]; shv[Nt] = shp[c]; w2v[Nt] = pw2[c];
    }
    v4f zero4 = {0.f, 0.f, 0.f, 0.f};
    v4f acc[4][4];
#pragma unroll
    for (int a = 0; a < 4; ++a)
#pragma unroll
        for (int c = 0; c < 4; ++c) acc[a][c] = zero4;

#pragma unroll
    for (int Ks = 0; Ks < 2; ++Ks) {
        v8s a[4], b[4];
#pragma unroll
        for (int Mt = 0; Mt < 4; ++Mt) {
            int bi = it0 + Mt * 16 + m;
            const unsigned short* r0 = hs + (size_t)(2 * bi) * HID + Ks * 32 + q * 8;
            v8s u0 = *(const v8s*)r0;
            v8s u1 = *(const v8s*)(r0 + HID);
            v8s av;
#pragma unroll
            for (int e = 0; e < 8; ++e) {
                float f = bf2f((unsigned short)u0[e]) + bf2f((unsigned short)u1[e]);
                av[e] = (short)f2bf(f);
            }
            a[Mt] = av;
        }
#pragma unroll
        for (int Nt = 0; Nt < 4; ++Nt)
            b[Nt] = *(const v8s*)(pw1t + (Nt * 16 + m) * HID + Ks * 32 + q * 8);
#pragma unroll
        for (int Mt = 0; Mt < 4; ++Mt)
#pragma unroll
            for (int Nt = 0; Nt < 4; ++Nt)
                acc[Mt][Nt] = __builtin_amdgcn_mfma_f32_16x16x32_bf16(a[Mt], b[Nt], acc[Mt][Nt], 0, 0, 0);
    }
    float pb2v = pb2[0];
#pragma unroll
    for (int Mt = 0; Mt < 4; ++Mt) {
#pragma unroll
        for (int j = 0; j < 4; ++j) {
            float po = 0.f;
#pragma unroll
            for (int Nt = 0; Nt < 4; ++Nt) {
                float ph = fmaxf(fmaf(acc[Mt][Nt][j], scv[Nt], shv[Nt]), 0.f);
                po = fmaf(ph, w2v[Nt], po);
            }
            po += __shfl_xor(po, 1);
            po += __shfl_xor(po, 2);
            po += __shfl_xor(po, 4);
            po += __shfl_xor(po, 8);
            if (m == 0) out[it0 + Mt * 16 + q * 4 + j] = po + pb2v;
        }
    }
}

extern "C" void kernel_launch(void* const* d_in, const int* in_sizes, int n_in,
                              void* d_out, int out_size, void* d_ws, size_t ws_size,
                              hipStream_t stream) {
    const int*   x     = (const int*)d_in[0];
    const int*   sql   = (const int*)d_in[1];
    const float* itab  = (const float*)d_in[2];
    const float* stab  = (const float*)d_in[3];
    const float* gw1   = (const float*)d_in[4];
    const float* gb1   = (const float*)d_in[5];
    const float* gw2   = (const float*)d_in[6];
    const float* gb2   = (const float*)d_in[7];
    const float* ew1   = (const float*)d_in[8];
    const float* eb1   = (const float*)d_in[9];
    const float* eg1   = (const float*)d_in[10];
    const float* ebe1  = (const float*)d_in[11];
    const float* em1   = (const float*)d_in[12];
    const float* ev1   = (const float*)d_in[13];
    const float* ew2   = (const float*)d_in[14];
    const float* eb2   = (const float*)d_in[15];
    const float* eg2   = (const float*)d_in[16];
    const float* ebe2  = (const float*)d_in[17];
    const float* em2   = (const float*)d_in[18];
    const float* ev2   = (const float*)d_in[19];
    const float* pw1   = (const float*)d_in[20];
    const float* pb1   = (const float*)d_in[21];
    const float* pg    = (const float*)d_in[22];
    const float* pbe   = (const float*)d_in[23];
    const float* pm    = (const float*)d_in[24];
    const float* pv    = (const float*)d_in[25];
    const float* pw2   = (const float*)d_in[26];
    const float* pb2   = (const float*)d_in[27];

    float* wsf = (float*)d_ws;
    int*   wsi = (int*)d_ws;
    int*   gcnt = wsi + OFF_GCNT;
    float* sc1 = wsf + OFF_SC1;
    float* sh1 = wsf + OFF_SH1;
    float* sc2 = wsf + OFF_SC2;
    float* sh2 = wsf + OFF_SH2;
    float* scp = wsf + OFF_SCP;
    float* shp = wsf + OFF_SHP;
    float* imp = wsf + OFF_IMP;
    int*   lidx = wsi + OFF_LIDX;
    float* lw  = wsf + OFF_LW;
    unsigned short* w1t   = (unsigned short*)(wsf + OFF_W1T);
    unsigned short* gw1t  = (unsigned short*)(wsf + OFF_GW1T);
    unsigned short* w2t   = (unsigned short*)(wsf + OFF_W2T);
    unsigned short* pw1t  = (unsigned short*)(wsf + OFF_PW1T);
    unsigned short* xembT = (unsigned short*)(wsf + OFF_XEMB);
    unsigned short* sqembT= (unsigned short*)(wsf + OFF_SQEMB);
    unsigned short* hs    = (unsigned short*)(wsf + OFF_HS);
    float* out = (float*)d_out;

    k_prep<<<1229, 256, 0, stream>>>(ew1, ew2, gw1, pw1,
                                     eb1, eg1, ebe1, em1, ev1,
                                     eb2, eg2, ebe2, em2, ev2,
                                     pb1, pg, pbe, pm, pv,
                                     wsf, gcnt, w1t, gw1t, w2t, pw1t);
    k_emb<<<57344, 256, 0, stream>>>(x, sql, itab, stab, xembT, sqembT);
    k_gate<<<NBLK_GATE, 256, 0, stream>>>(sqembT, gw1t, gb1, gw2, gb2,
                                          lidx, lw, gcnt, imp);
    k_loss<<<1, 256, 0, stream>>>(imp, out);
    k_pad<<<16, 64, 0, stream>>>(gcnt, lidx, lw);
    dim3 ge(NBX_EXP, KEXP);
    k_exp<<<ge, 256, 0, stream>>>(xembT, w1t, w2t, sc1, sh1, sc2, sh2,
                                  lidx, lw, gcnt, hs);
    k_head<<<256, 256, 0, stream>>>(hs, pw1t, scp, shp, pw2, pb2, out);
}

// Round 6
// 153.194 us; speedup vs baseline: 2.2118x; 1.0053x over previous
//
#include <hip/hip_runtime.h>
#include <hip/hip_bf16.h>

#define BB 65536
#define NFIELD 20
#define HID 64
#define KEXP 16
#define EPS 1e-5f
#define KPAD 224
#define NKS 7            // 224/32 K-steps
#define NBLK_GATE 256
#define NBX_EXP 40
#define EMB_BPB 16       // samples per k_emb block

typedef __attribute__((ext_vector_type(8))) short v8s;   // 8 bf16
typedef __attribute__((ext_vector_type(4))) float v4f;

// ---- ws layout (4B element offsets) ----
#define OFF_GCNT 0
#define OFF_SC1 64
#define OFF_SH1 1088
#define OFF_SC2 2112
#define OFF_SH2 3136
#define OFF_SCP 4160
#define OFF_SHP 4224
#define OFF_IMP 4288            // 256*16
#define OFF_LIDX 8448           // 16*BB int
#define OFF_LW  1057024         // 16*BB f32
#define OFF_W1T 2105600         // 16*64*224 bf16
#define OFF_GW1T 2220288        // 64*224 bf16
#define OFF_W2T 2227456         // 16*64*64 bf16
#define OFF_PW1T 2260224        // 64*64 bf16
#define OFF_XEMB 2262272        // 65537*224 bf16
#define OFF_SQEMB 9602416       // 65536*224 bf16
#define OFF_HS 16942448         // 131073*64 bf16

__device__ __forceinline__ unsigned short f2bf(float f) {
    unsigned int u = __float_as_uint(f);
    unsigned int r = (u + 0x7FFFu + ((u >> 16) & 1u)) >> 16;
    return (unsigned short)r;
}
__device__ __forceinline__ float bf2f(unsigned short u) {
    unsigned int t = ((unsigned int)u) << 16;
    return __uint_as_float(t);
}

// ---------------- prep: BN folds + bf16 weight transposes + gcnt zero ----------------
__global__ __launch_bounds__(256) void k_prep(
    const float* __restrict__ ew1, const float* __restrict__ ew2,
    const float* __restrict__ gw1, const float* __restrict__ pw1,
    const float* __restrict__ eb1, const float* __restrict__ eg1,
    const float* __restrict__ ebe1, const float* __restrict__ em1,
    const float* __restrict__ ev1,
    const float* __restrict__ eb2, const float* __restrict__ eg2,
    const float* __restrict__ ebe2, const float* __restrict__ em2,
    const float* __restrict__ ev2,
    const float* __restrict__ pb1, const float* __restrict__ pg,
    const float* __restrict__ pbe, const float* __restrict__ pm,
    const float* __restrict__ pv,
    float* __restrict__ wsf, int* __restrict__ gcnt,
    unsigned short* __restrict__ w1t, unsigned short* __restrict__ gw1t,
    unsigned short* __restrict__ w2t, unsigned short* __restrict__ pw1t)
{
    int gid = blockIdx.x * 256 + threadIdx.x;
    if (gid < 229376) {               // W1T[k][c][t] = ew1[k][t][c]
        int k = gid / 14336, r = gid % 14336, c = r / KPAD, t = r % KPAD;
        w1t[gid] = (t < 200) ? f2bf(ew1[((size_t)k * 200 + t) * HID + c]) : 0;
    } else if (gid < 229376 + 14336) { // gw1T[c][t]
        int g2 = gid - 229376; int c = g2 / KPAD, t = g2 % KPAD;
        gw1t[g2] = (t < 200) ? f2bf(gw1[t * HID + c]) : 0;
    } else if (gid < 243712 + 65536) { // W2T[k][g][i] = ew2[k][i][g]
        int g2 = gid - 243712; int k = g2 / 4096, r = g2 % 4096, g = r / 64, i = r % 64;
        w2t[g2] = f2bf(ew2[((size_t)k * 64 + i) * 64 + g]);
    } else if (gid < 309248 + 4096) {  // PW1T[g][i] = pw1[i][g]
        int g2 = gid - 309248; int g = g2 / 64, i = g2 % 64;
        pw1t[g2] = f2bf(pw1[i * 64 + g]);
    } else if (gid < 313344 + 1024) {
        int t = gid - 313344;
        float rs1 = rsqrtf(ev1[t] + EPS) * eg1[t];
        wsf[OFF_SC1 + t] = rs1;
        wsf[OFF_SH1 + t] = fmaf(eb1[t] - em1[t], rs1, ebe1[t]);
        float rs2 = rsqrtf(ev2[t] + EPS) * eg2[t];
        wsf[OFF_SC2 + t] = rs2;
        wsf[OFF_SH2 + t] = fmaf(eb2[t] - em2[t], rs2, ebe2[t]);
    } else if (gid < 314368 + 64) {
        int t = gid - 314368;
        float rs = rsqrtf(pv[t] + EPS) * pg[t];
        wsf[OFF_SCP + t] = rs;
        wsf[OFF_SHP + t] = fmaf(pb1[t] - pm[t], rs, pbe[t]);
    } else if (gid < 314432 + 16) {
        gcnt[gid - 314432] = 0;
    }
}

// ---------------- gathers -> bf16 padded embedding matrices ----------------
// one thread per (sample, field) row: 1 idx load + 5 independent float2 loads,
// LDS staging tile, coalesced uint4 stores. Tail cols [200,224) pre-zeroed.
__global__ __launch_bounds__(256) void k_emb(
    const int* __restrict__ x, const int* __restrict__ sql,
    const float* __restrict__ itab, const float* __restrict__ stab,
    unsigned short* __restrict__ xembT, unsigned short* __restrict__ sqembT)
{
    __shared__ unsigned int lbuf[EMB_BPB * 112];   // 16 rows * 448B = 7168 B
    int blk = blockIdx.x;
    int sel = blk >= (BB / EMB_BPB);
    int b0 = (sel ? blk - (BB / EMB_BPB) : blk) * EMB_BPB;
    const int* idxp = sel ? sql : x;
    const float* tab = sel ? stab : itab;
    unsigned short* dst = sel ? sqembT : xembT;
    int tid = threadIdx.x;

    if (tid < EMB_BPB * 12)                         // zero pad cols 200..223
        lbuf[(tid / 12) * 112 + 100 + (tid % 12)] = 0;

    for (int r = tid; r < EMB_BPB * NFIELD; r += 256) {
        int lb = r / NFIELD, f = r % NFIELD;
        int idx = idxp[b0 * NFIELD + r];            // coalesced
        const float* row = tab + (size_t)idx * 10;
        unsigned int* lrow = &lbuf[lb * 112 + f * 5];
        float2 t0 = *(const float2*)(row + 0);
        float2 t1 = *(const float2*)(row + 2);
        float2 t2 = *(const float2*)(row + 4);
        float2 t3 = *(const float2*)(row + 6);
        float2 t4 = *(const float2*)(row + 8);
        lrow[0] = (unsigned int)f2bf(t0.x) | ((unsigned int)f2bf(t0.y) << 16);
        lrow[1] = (unsigned int)f2bf(t1.x) | ((unsigned int)f2bf(t1.y) << 16);
        lrow[2] = (unsigned int)f2bf(t2.x) | ((unsigned int)f2bf(t2.y) << 16);
        lrow[3] = (unsigned int)f2bf(t3.x) | ((unsigned int)f2bf(t3.y) << 16);
        lrow[4] = (unsigned int)f2bf(t4.x) | ((unsigned int)f2bf(t4.y) << 16);
    }
    __syncthreads();
    uint4* g4 = (uint4*)(dst + (size_t)b0 * KPAD);
    const uint4* l4 = (const uint4*)lbuf;
    g4[tid] = l4[tid];                               // 448 uint4 total
    if (tid < EMB_BPB * 112 / 4 - 256) g4[256 + tid] = l4[256 + tid];
}

// ---------------- gate: MFMA L1 + per-lane logits/softmax/top2 + list build ----------------
__global__ __launch_bounds__(256, 2) void k_gate(
    const unsigned short* __restrict__ sqembT, const unsigned short* __restrict__ gw1t,
    const float* __restrict__ gb1, const float* __restrict__ gw2,
    const float* __restrict__ gb2,
    int* __restrict__ lidx, float* __restrict__ lw,
    int* __restrict__ gcnt, float* __restrict__ imp_part)
{
    __shared__ unsigned short Hg[4][64][80];
    __shared__ float s_imp[KEXP];
    __shared__ int s_cnt[KEXP];
    __shared__ int s_base[KEXP];
    int tid = threadIdx.x;
    int wid = tid >> 6, l = tid & 63;
    int m = l & 15, q = l >> 4;
    if (tid < KEXP) { s_imp[tid] = 0.f; s_cnt[tid] = 0; }
    __syncthreads();

    int it0 = blockIdx.x * 256 + wid * 64;
    v4f zero4 = {0.f, 0.f, 0.f, 0.f};
    v4f acc[4][4];
#pragma unroll
    for (int a = 0; a < 4; ++a)
#pragma unroll
        for (int c = 0; c < 4; ++c) acc[a][c] = zero4;

    const unsigned short* Ab = sqembT + (size_t)it0 * KPAD + q * 8;
    const unsigned short* Bb = gw1t + m * KPAD + q * 8;
#pragma unroll
    for (int Ks = 0; Ks < NKS; ++Ks) {
        v8s a[4], b[4];
#pragma unroll
        for (int Mt = 0; Mt < 4; ++Mt)
            a[Mt] = *(const v8s*)(Ab + (Mt * 16 + m) * KPAD + Ks * 32);
#pragma unroll
        for (int Nt = 0; Nt < 4; ++Nt)
            b[Nt] = *(const v8s*)(Bb + Nt * 16 * KPAD + Ks * 32);
#pragma unroll
        for (int Mt = 0; Mt < 4; ++Mt)
#pragma unroll
            for (int Nt = 0; Nt < 4; ++Nt)
                acc[Mt][Nt] = __builtin_amdgcn_mfma_f32_16x16x32_bf16(a[Mt], b[Nt], acc[Mt][Nt], 0, 0, 0);
    }
    // bias + relu -> swizzled LDS (bf16)
#pragma unroll
    for (int Nt = 0; Nt < 4; ++Nt) {
        int c = Nt * 16 + m;
        float bias = gb1[c];
#pragma unroll
        for (int Mt = 0; Mt < 4; ++Mt)
#pragma unroll
            for (int j = 0; j < 4; ++j) {
                int item = Mt * 16 + q * 4 + j;
                float v = fmaxf(acc[Mt][Nt][j] + bias, 0.f);
                Hg[wid][item][c ^ ((item & 7) << 3)] = f2bf(v);
            }
    }
    // per-lane: logits for item = it0 + l
    float z[KEXP];
#pragma unroll
    for (int j = 0; j < KEXP; ++j) z[j] = gb2[j];
#pragma unroll
    for (int u = 0; u < 8; ++u) {
        v8s hv = *(const v8s*)&Hg[wid][l][(u * 8) ^ ((l & 7) << 3)];
#pragma unroll
        for (int e = 0; e < 8; ++e) {
            int h = u * 8 + e;
            float g = bf2f((unsigned short)hv[e]);
#pragma unroll
            for (int j = 0; j < KEXP; ++j) z[j] = fmaf(g, gw2[h * KEXP + j], z[j]);
        }
    }
    float mm = z[0];
#pragma unroll
    for (int j = 1; j < KEXP; ++j) mm = fmaxf(mm, z[j]);
    float s = 0.f;
#pragma unroll
    for (int j = 0; j < KEXP; ++j) s += expf(z[j] - mm);
    int i0 = 0; float m0 = z[0];
#pragma unroll
    for (int j = 1; j < KEXP; ++j) if (z[j] > m0) { m0 = z[j]; i0 = j; }
    int i1 = (i0 == 0) ? 1 : 0; float m1 = -3.4e38f;
#pragma unroll
    for (int j = 0; j < KEXP; ++j) if (j != i0 && z[j] > m1) { m1 = z[j]; i1 = j; }
    float v0 = expf(m0 - mm) / s, v1 = expf(m1 - mm) / s;
    float inv = 1.f / (v0 + v1 + 1e-9f);
    float w0 = v0 * inv, w1 = v1 * inv;

    int b = blockIdx.x * 256 + tid;
    atomicAdd(&s_imp[i0], w0);
    atomicAdd(&s_imp[i1], w1);
    int o0 = atomicAdd(&s_cnt[i0], 1);
    int o1 = atomicAdd(&s_cnt[i1], 1);
    __syncthreads();
    if (tid < KEXP) {
        imp_part[blockIdx.x * KEXP + tid] = s_imp[tid];
        s_base[tid] = atomicAdd(&gcnt[tid], s_cnt[tid]);
    }
    __syncthreads();
    int p0 = i0 * BB + s_base[i0] + o0;
    lidx[p0] = (b << 1);     lw[p0] = w0;
    int p1 = i1 * BB + s_base[i1] + o1;
    lidx[p1] = (b << 1) | 1; lw[p1] = w1;
}

// ---------------- pad each expert list to multiple of 64 with benign entries ----------------
__global__ void k_pad(const int* __restrict__ gcnt, int* __restrict__ lidx,
                      float* __restrict__ lw)
{
    int k = blockIdx.x;
    int n = gcnt[k];
    int ne = (n + 63) & ~63;
    for (int i = n + threadIdx.x; i < ne; i += 64) {
        lidx[k * BB + i] = 2 * BB;   // dedicated pad row
        lw[k * BB + i] = 0.f;
    }
}

// ---------------- loss ----------------
__global__ __launch_bounds__(256) void k_loss(const float* __restrict__ imp_part,
                                              float* __restrict__ out)
{
    __shared__ double sred[16][17];
    __shared__ double simp[KEXP];
    int tid = threadIdx.x;
    int j = tid & 15, g = tid >> 4;
    double s = 0.0;
    for (int blk = g; blk < NBLK_GATE; blk += 16) s += (double)imp_part[blk * KEXP + j];
    sred[g][j] = s;
    __syncthreads();
    if (tid < KEXP) {
        double t = 0.0;
#pragma unroll
        for (int gg = 0; gg < 16; ++gg) t += sred[gg][tid];
        simp[tid] = t;
    }
    __syncthreads();
    if (tid == 0) {
        double mean = 0.0;
        for (int jj = 0; jj < KEXP; ++jj) mean += simp[jj];
        mean /= KEXP;
        double var = 0.0;
        for (int jj = 0; jj < KEXP; ++jj) { double d = simp[jj] - mean; var += d * d; }
        var /= KEXP;
        out[BB] = (float)(var / (mean * mean + 1e-10));
    }
}

// ---------------- fused expert: MFMA L1 -> LDS -> MFMA L2 -> hs (bf16) ----------------
__global__ __launch_bounds__(256, 2) void k_exp(
    const unsigned short* __restrict__ xembT,
    const unsigned short* __restrict__ w1t, const unsigned short* __restrict__ w2t,
    const float* __restrict__ sc1, const float* __restrict__ sh1,
    const float* __restrict__ sc2, const float* __restrict__ sh2,
    const int* __restrict__ lidx, const float* __restrict__ lw,
    const int* __restrict__ gcnt, unsigned short* __restrict__ hs)
{
    __shared__ unsigned short Hl[4][64][80];
    int k = blockIdx.y;
    int tid = threadIdx.x;
    int wid = tid >> 6, l = tid & 63;
    int m = l & 15, q = l >> 4;
    int n = gcnt[k];
    int ne = (n + 63) & ~63;
    const unsigned short* W1 = w1t + (size_t)k * 64 * KPAD + m * KPAD + q * 8;
    const unsigned short* W2 = w2t + (size_t)k * 64 * 64 + m * 64 + q * 8;
    float sc1v[4], sh1v[4], sc2v[4], sh2v[4];
#pragma unroll
    for (int Nt = 0; Nt < 4; ++Nt) {
        int c = Nt * 16 + m;
        sc1v[Nt] = sc1[k * HID + c]; sh1v[Nt] = sh1[k * HID + c];
        sc2v[Nt] = sc2[k * HID + c]; sh2v[Nt] = sh2[k * HID + c];
    }
    v4f zero4 = {0.f, 0.f, 0.f, 0.f};

    for (int it0 = (blockIdx.x * 4 + wid) * 64; it0 < ne; it0 += NBX_EXP * 256) {
        // ---- layer 1 ----
        int eA[4];
#pragma unroll
        for (int Mt = 0; Mt < 4; ++Mt) eA[Mt] = lidx[k * BB + it0 + Mt * 16 + m];
        v4f acc1[4][4];
#pragma unroll
        for (int a = 0; a < 4; ++a)
#pragma unroll
            for (int c = 0; c < 4; ++c) acc1[a][c] = zero4;
#pragma unroll
        for (int Ks = 0; Ks < NKS; ++Ks) {
            v8s a[4], b[4];
#pragma unroll
            for (int Mt = 0; Mt < 4; ++Mt)
                a[Mt] = *(const v8s*)(xembT + (size_t)(eA[Mt] >> 1) * KPAD + Ks * 32 + q * 8);
#pragma unroll
            for (int Nt = 0; Nt < 4; ++Nt)
                b[Nt] = *(const v8s*)(W1 + Nt * 16 * KPAD + Ks * 32);
#pragma unroll
            for (int Mt = 0; Mt < 4; ++Mt)
#pragma unroll
                for (int Nt = 0; Nt < 4; ++Nt)
                    acc1[Mt][Nt] = __builtin_amdgcn_mfma_f32_16x16x32_bf16(a[Mt], b[Nt], acc1[Mt][Nt], 0, 0, 0);
        }
        // BN1 + relu -> swizzled LDS
#pragma unroll
        for (int Nt = 0; Nt < 4; ++Nt) {
            int c = Nt * 16 + m;
#pragma unroll
            for (int Mt = 0; Mt < 4; ++Mt)
#pragma unroll
                for (int j = 0; j < 4; ++j) {
                    int item = Mt * 16 + q * 4 + j;
                    float v = fmaxf(fmaf(acc1[Mt][Nt][j], sc1v[Nt], sh1v[Nt]), 0.f);
                    Hl[wid][item][c ^ ((item & 7) << 3)] = f2bf(v);
                }
        }
        // ---- layer 2 (K=64) ----
        v4f acc2[4][4];
#pragma unroll
        for (int a = 0; a < 4; ++a)
#pragma unroll
            for (int c = 0; c < 4; ++c) acc2[a][c] = zero4;
#pragma unroll
        for (int Ks = 0; Ks < 2; ++Ks) {
            v8s a[4], b[4];
#pragma unroll
            for (int Mt = 0; Mt < 4; ++Mt)
                a[Mt] = *(const v8s*)&Hl[wid][Mt * 16 + m][(Ks * 32 + q * 8) ^ ((m & 7) << 3)];
#pragma unroll
            for (int Nt = 0; Nt < 4; ++Nt)
                b[Nt] = *(const v8s*)(W2 + Nt * 16 * 64 + Ks * 32);
#pragma unroll
            for (int Mt = 0; Mt < 4; ++Mt)
#pragma unroll
                for (int Nt = 0; Nt < 4; ++Nt)
                    acc2[Mt][Nt] = __builtin_amdgcn_mfma_f32_16x16x32_bf16(a[Mt], b[Nt], acc2[Mt][Nt], 0, 0, 0);
        }
        // BN2 + relu, * gate weight -> swizzled LDS (reuse)
#pragma unroll
        for (int Mt = 0; Mt < 4; ++Mt) {
            float4 wC = *(const float4*)&lw[k * BB + it0 + Mt * 16 + q * 4];
            float wj[4] = {wC.x, wC.y, wC.z, wC.w};
#pragma unroll
            for (int Nt = 0; Nt < 4; ++Nt) {
                int c = Nt * 16 + m;
#pragma unroll
                for (int j = 0; j < 4; ++j) {
                    int item = Mt * 16 + q * 4 + j;
                    float v = wj[j] * fmaxf(fmaf(acc2[Mt][Nt][j], sc2v[Nt], sh2v[Nt]), 0.f);
                    Hl[wid][item][c ^ ((item & 7) << 3)] = f2bf(v);
                }
            }
        }
        // per-lane: write own row to hs[e][64] (coalesced 16B chunks)
        int eo = lidx[k * BB + it0 + l];
        unsigned short* hrow = hs + (size_t)eo * HID;
#pragma unroll
        for (int u = 0; u < 8; ++u)
            *(v8s*)(hrow + u * 8) = *(const v8s*)&Hl[wid][l][(u * 8) ^ ((l & 7) << 3)];
    }
}

// ---------------- head: sum slots + MFMA (K=64) + BN/relu + dot pw2 ----------------
__global__ __launch_bounds__(256, 2) void k_head(
    const unsigned short* __restrict__ hs, const unsigned short* __restrict__ pw1t,
    const float* __restrict__ scp, const float* __restrict__ shp,
    const float* __restrict__ pw2, const float* __restrict__ pb2,
    float* __restrict__ out)
{
    int tid = threadIdx.x;
    int wid = tid >> 6, l = tid & 63;
    int m = l & 15, q = l >> 4;
    int it0 = blockIdx.x * 256 + wid * 64;
    float scv[4], shv[4], w2v[4];
#pragma unroll
    for (int Nt = 0; Nt < 4; ++Nt) {
        int c = Nt * 16 + m;
        scv[Nt] = scp[c]; shv[Nt] = shp[c]; w2v[Nt] = pw2[c];
    }
    v4f zero4 = {0.f, 0.f, 0.f, 0.f};
    v4f acc[4][4];
#pragma unroll
    for (int a = 0; a < 4; ++a)
#pragma unroll
        for (int c = 0; c < 4; ++c) acc[a][c] = zero4;

#pragma unroll
    for (int Ks = 0; Ks < 2; ++Ks) {
        v8s a[4], b[4];
#pragma unroll
        for (int Mt = 0; Mt < 4; ++Mt) {
            int bi = it0 + Mt * 16 + m;
            const unsigned short* r0 = hs + (size_t)(2 * bi) * HID + Ks * 32 + q * 8;
            v8s u0 = *(const v8s*)r0;
            v8s u1 = *(const v8s*)(r0 + HID);
            v8s av;
#pragma unroll
            for (int e = 0; e < 8; ++e) {
                float f = bf2f((unsigned short)u0[e]) + bf2f((unsigned short)u1[e]);
                av[e] = (short)f2bf(f);
            }
            a[Mt] = av;
        }
#pragma unroll
        for (int Nt = 0; Nt < 4; ++Nt)
            b[Nt] = *(const v8s*)(pw1t + (Nt * 16 + m) * HID + Ks * 32 + q * 8);
#pragma unroll
        for (int Mt = 0; Mt < 4; ++Mt)
#pragma unroll
            for (int Nt = 0; Nt < 4; ++Nt)
                acc[Mt][Nt] = __builtin_amdgcn_mfma_f32_16x16x32_bf16(a[Mt], b[Nt], acc[Mt][Nt], 0, 0, 0);
    }
    float pb2v = pb2[0];
#pragma unroll
    for (int Mt = 0; Mt < 4; ++Mt) {
#pragma unroll
        for (int j = 0; j < 4; ++j) {
            float po = 0.f;
#pragma unroll
            for (int Nt = 0; Nt < 4; ++Nt) {
                float ph = fmaxf(fmaf(acc[Mt][Nt][j], scv[Nt], shv[Nt]), 0.f);
                po = fmaf(ph, w2v[Nt], po);
            }
            po += __shfl_xor(po, 1);
            po += __shfl_xor(po, 2);
            po += __shfl_xor(po, 4);
            po += __shfl_xor(po, 8);
            if (m == 0) out[it0 + Mt * 16 + q * 4 + j] = po + pb2v;
        }
    }
}

extern "C" void kernel_launch(void* const* d_in, const int* in_sizes, int n_in,
                              void* d_out, int out_size, void* d_ws, size_t ws_size,
                              hipStream_t stream) {
    const int*   x     = (const int*)d_in[0];
    const int*   sql   = (const int*)d_in[1];
    const float* itab  = (const float*)d_in[2];
    const float* stab  = (const float*)d_in[3];
    const float* gw1   = (const float*)d_in[4];
    const float* gb1   = (const float*)d_in[5];
    const float* gw2   = (const float*)d_in[6];
    const float* gb2   = (const float*)d_in[7];
    const float* ew1   = (const float*)d_in[8];
    const float* eb1   = (const float*)d_in[9];
    const float* eg1   = (const float*)d_in[10];
    const float* ebe1  = (const float*)d_in[11];
    const float* em1   = (const float*)d_in[12];
    const float* ev1   = (const float*)d_in[13];
    const float* ew2   = (const float*)d_in[14];
    const float* eb2   = (const float*)d_in[15];
    const float* eg2   = (const float*)d_in[16];
    const float* ebe2  = (const float*)d_in[17];
    const float* em2   = (const float*)d_in[18];
    const float* ev2   = (const float*)d_in[19];
    const float* pw1   = (const float*)d_in[20];
    const float* pb1   = (const float*)d_in[21];
    const float* pg    = (const float*)d_in[22];
    const float* pbe   = (const float*)d_in[23];
    const float* pm    = (const float*)d_in[24];
    const float* pv    = (const float*)d_in[25];
    const float* pw2   = (const float*)d_in[26];
    const float* pb2   = (const float*)d_in[27];

    float* wsf = (float*)d_ws;
    int*   wsi = (int*)d_ws;
    int*   gcnt = wsi + OFF_GCNT;
    float* sc1 = wsf + OFF_SC1;
    float* sh1 = wsf + OFF_SH1;
    float* sc2 = wsf + OFF_SC2;
    float* sh2 = wsf + OFF_SH2;
    float* scp = wsf + OFF_SCP;
    float* shp = wsf + OFF_SHP;
    float* imp = wsf + OFF_IMP;
    int*   lidx = wsi + OFF_LIDX;
    float* lw  = wsf + OFF_LW;
    unsigned short* w1t   = (unsigned short*)(wsf + OFF_W1T);
    unsigned short* gw1t  = (unsigned short*)(wsf + OFF_GW1T);
    unsigned short* w2t   = (unsigned short*)(wsf + OFF_W2T);
    unsigned short* pw1t  = (unsigned short*)(wsf + OFF_PW1T);
    unsigned short* xembT = (unsigned short*)(wsf + OFF_XEMB);
    unsigned short* sqembT= (unsigned short*)(wsf + OFF_SQEMB);
    unsigned short* hs    = (unsigned short*)(wsf + OFF_HS);
    float* out = (float*)d_out;

    k_prep<<<1229, 256, 0, stream>>>(ew1, ew2, gw1, pw1,
                                     eb1, eg1, ebe1, em1, ev1,
                                     eb2, eg2, ebe2, em2, ev2,
                                     pb1, pg, pbe, pm, pv,
                                     wsf, gcnt, w1t, gw1t, w2t, pw1t);
    k_emb<<<2 * (BB / EMB_BPB), 256, 0, stream>>>(x, sql, itab, stab, xembT, sqembT);
    k_gate<<<NBLK_GATE, 256, 0, stream>>>(sqembT, gw1t, gb1, gw2, gb2,
                                          lidx, lw, gcnt, imp);
    k_loss<<<1, 256, 0, stream>>>(imp, out);
    k_pad<<<16, 64, 0, stream>>>(gcnt, lidx, lw);
    dim3 ge(NBX_EXP, KEXP);
    k_exp<<<ge, 256, 0, stream>>>(xembT, w1t, w2t, sc1, sh1, sc2, sh2,
                                  lidx, lw, gcnt, hs);
    k_head<<<256, 256, 0, stream>>>(hs, pw1t, scp, shp, pw2, pb2, out);
}

// Round 7
// 150.856 us; speedup vs baseline: 2.2461x; 1.0155x over previous
//
#include <hip/hip_runtime.h>
#include <hip/hip_bf16.h>

#define BB 65536
#define NFIELD 20
#define HID 64
#define KEXP 16
#define EPS 1e-5f
#define KPAD 224
#define NKS 7            // 224/32 K-steps
#define NBLK_GATE 1024   // 64 samples per gate block
#define NBX_EXP 40
#define EMB_BPB 16       // samples per k_emb block
#define TSTR 228         // gate LDS tile stride (bf16) -> 2-way max bank aliasing

typedef __attribute__((ext_vector_type(8))) short v8s;   // 8 bf16
typedef __attribute__((ext_vector_type(4))) float v4f;

// ---- ws layout (4B element offsets) ----
#define OFF_GCNT 0
#define OFF_SC1 64
#define OFF_SH1 1088
#define OFF_SC2 2112
#define OFF_SH2 3136
#define OFF_SCP 4160
#define OFF_SHP 4224
#define OFF_IMP 4288            // 1024*16 f32
#define OFF_LIDX 20672          // 16*BB int
#define OFF_LW  1069248         // 16*BB f32
#define OFF_W1T 2117824         // 16*64*224 bf16
#define OFF_GW1T 2232512        // 64*224 bf16
#define OFF_W2T 2239680         // 16*64*64 bf16
#define OFF_PW1T 2272448        // 64*64 bf16
#define OFF_XEMB 2274496        // 65537*224 bf16
#define OFF_HS 9614640          // 131073*64 bf16

__device__ __forceinline__ unsigned short f2bf(float f) {
    unsigned int u = __float_as_uint(f);
    unsigned int r = (u + 0x7FFFu + ((u >> 16) & 1u)) >> 16;
    return (unsigned short)r;
}
__device__ __forceinline__ float bf2f(unsigned short u) {
    unsigned int t = ((unsigned int)u) << 16;
    return __uint_as_float(t);
}

// ---------------- prep: BN folds + bf16 weight transposes + gcnt zero ----------------
__global__ __launch_bounds__(256) void k_prep(
    const float* __restrict__ ew1, const float* __restrict__ ew2,
    const float* __restrict__ gw1, const float* __restrict__ pw1,
    const float* __restrict__ eb1, const float* __restrict__ eg1,
    const float* __restrict__ ebe1, const float* __restrict__ em1,
    const float* __restrict__ ev1,
    const float* __restrict__ eb2, const float* __restrict__ eg2,
    const float* __restrict__ ebe2, const float* __restrict__ em2,
    const float* __restrict__ ev2,
    const float* __restrict__ pb1, const float* __restrict__ pg,
    const float* __restrict__ pbe, const float* __restrict__ pm,
    const float* __restrict__ pv,
    float* __restrict__ wsf, int* __restrict__ gcnt,
    unsigned short* __restrict__ w1t, unsigned short* __restrict__ gw1t,
    unsigned short* __restrict__ w2t, unsigned short* __restrict__ pw1t)
{
    int gid = blockIdx.x * 256 + threadIdx.x;
    if (gid < 229376) {               // W1T[k][c][t] = ew1[k][t][c]
        int k = gid / 14336, r = gid % 14336, c = r / KPAD, t = r % KPAD;
        w1t[gid] = (t < 200) ? f2bf(ew1[((size_t)k * 200 + t) * HID + c]) : 0;
    } else if (gid < 229376 + 14336) { // gw1T[c][t]
        int g2 = gid - 229376; int c = g2 / KPAD, t = g2 % KPAD;
        gw1t[g2] = (t < 200) ? f2bf(gw1[t * HID + c]) : 0;
    } else if (gid < 243712 + 65536) { // W2T[k][g][i] = ew2[k][i][g]
        int g2 = gid - 243712; int k = g2 / 4096, r = g2 % 4096, g = r / 64, i = r % 64;
        w2t[g2] = f2bf(ew2[((size_t)k * 64 + i) * 64 + g]);
    } else if (gid < 309248 + 4096) {  // PW1T[g][i] = pw1[i][g]
        int g2 = gid - 309248; int g = g2 / 64, i = g2 % 64;
        pw1t[g2] = f2bf(pw1[i * 64 + g]);
    } else if (gid < 313344 + 1024) {
        int t = gid - 313344;
        float rs1 = rsqrtf(ev1[t] + EPS) * eg1[t];
        wsf[OFF_SC1 + t] = rs1;
        wsf[OFF_SH1 + t] = fmaf(eb1[t] - em1[t], rs1, ebe1[t]);
        float rs2 = rsqrtf(ev2[t] + EPS) * eg2[t];
        wsf[OFF_SC2 + t] = rs2;
        wsf[OFF_SH2 + t] = fmaf(eb2[t] - em2[t], rs2, ebe2[t]);
    } else if (gid < 314368 + 64) {
        int t = gid - 314368;
        float rs = rsqrtf(pv[t] + EPS) * pg[t];
        wsf[OFF_SCP + t] = rs;
        wsf[OFF_SHP + t] = fmaf(pb1[t] - pm[t], rs, pbe[t]);
    } else if (gid < 314432 + 16) {
        gcnt[gid - 314432] = 0;
    }
}

// ---------------- x gather -> bf16 padded xembT ----------------
__global__ __launch_bounds__(256) void k_emb(
    const int* __restrict__ x, const float* __restrict__ itab,
    unsigned short* __restrict__ xembT)
{
    __shared__ unsigned int lbuf[EMB_BPB * 112];   // 16 rows * 448B = 7168 B
    int b0 = blockIdx.x * EMB_BPB;
    int tid = threadIdx.x;

    if (tid < EMB_BPB * 12)                         // zero pad cols 200..223
        lbuf[(tid / 12) * 112 + 100 + (tid % 12)] = 0;

    for (int r = tid; r < EMB_BPB * NFIELD; r += 256) {
        int lb = r / NFIELD, f = r % NFIELD;
        int idx = x[b0 * NFIELD + r];               // coalesced
        const float* row = itab + (size_t)idx * 10;
        unsigned int* lrow = &lbuf[lb * 112 + f * 5];
        float2 t0 = *(const float2*)(row + 0);
        float2 t1 = *(const float2*)(row + 2);
        float2 t2 = *(const float2*)(row + 4);
        float2 t3 = *(const float2*)(row + 6);
        float2 t4 = *(const float2*)(row + 8);
        lrow[0] = (unsigned int)f2bf(t0.x) | ((unsigned int)f2bf(t0.y) << 16);
        lrow[1] = (unsigned int)f2bf(t1.x) | ((unsigned int)f2bf(t1.y) << 16);
        lrow[2] = (unsigned int)f2bf(t2.x) | ((unsigned int)f2bf(t2.y) << 16);
        lrow[3] = (unsigned int)f2bf(t3.x) | ((unsigned int)f2bf(t3.y) << 16);
        lrow[4] = (unsigned int)f2bf(t4.x) | ((unsigned int)f2bf(t4.y) << 16);
    }
    __syncthreads();
    uint4* g4 = (uint4*)(xembT + (size_t)b0 * KPAD);
    const uint4* l4 = (const uint4*)lbuf;
    g4[tid] = l4[tid];                               // 448 uint4 total
    if (tid < EMB_BPB * 112 / 4 - 256) g4[256 + tid] = l4[256 + tid];
}

// ---------------- fused gate: sql gather -> LDS -> MFMA -> softmax/top2/list ----------------
__global__ __launch_bounds__(256) void k_gate(
    const int* __restrict__ sql, const float* __restrict__ stab,
    const unsigned short* __restrict__ gw1t,
    const float* __restrict__ gb1, const float* __restrict__ gw2,
    const float* __restrict__ gb2,
    int* __restrict__ lidx, float* __restrict__ lw,
    int* __restrict__ gcnt, float* __restrict__ imp_part)
{
    __shared__ unsigned short tile[64][TSTR];       // 29184 B; Hg overlaid after MFMA
    __shared__ float s_imp[KEXP];
    __shared__ int s_cnt[KEXP];
    __shared__ int s_base[KEXP];
    unsigned short (*Hg)[80] = (unsigned short (*)[80])&tile[0][0];
    int tid = threadIdx.x;
    int wid = tid >> 6, l = tid & 63;
    int m = l & 15, q = l >> 4;
    int b0 = blockIdx.x * 64;

    if (tid < KEXP) { s_imp[tid] = 0.f; s_cnt[tid] = 0; }
    // zero pad cols 200..223
    for (int t = tid; t < 64 * 12; t += 256) {
        int r = t / 12, c2 = t % 12;
        *(unsigned int*)&tile[r][200 + 2 * c2] = 0;
    }
    // gather 64*20 = 1280 sql rows, 5 per thread (25 loads in flight)
#pragma unroll
    for (int rr = 0; rr < 5; ++rr) {
        int r = tid + rr * 256;
        int lb = r / NFIELD, f = r % NFIELD;
        int idx = sql[(size_t)(b0 + lb) * NFIELD + f];
        const float* row = stab + (size_t)idx * 10;
        float2 t0 = *(const float2*)(row + 0);
        float2 t1 = *(const float2*)(row + 2);
        float2 t2 = *(const float2*)(row + 4);
        float2 t3 = *(const float2*)(row + 6);
        float2 t4 = *(const float2*)(row + 8);
        unsigned int* lrow = (unsigned int*)&tile[lb][f * 10];
        lrow[0] = (unsigned int)f2bf(t0.x) | ((unsigned int)f2bf(t0.y) << 16);
        lrow[1] = (unsigned int)f2bf(t1.x) | ((unsigned int)f2bf(t1.y) << 16);
        lrow[2] = (unsigned int)f2bf(t2.x) | ((unsigned int)f2bf(t2.y) << 16);
        lrow[3] = (unsigned int)f2bf(t3.x) | ((unsigned int)f2bf(t3.y) << 16);
        lrow[4] = (unsigned int)f2bf(t4.x) | ((unsigned int)f2bf(t4.y) << 16);
    }
    __syncthreads();

    // MFMA: 64 samples x 16 cols (this wave) x K=224
    v4f zero4 = {0.f, 0.f, 0.f, 0.f};
    v4f acc[4];
#pragma unroll
    for (int a = 0; a < 4; ++a) acc[a] = zero4;
    const unsigned short* Bb = gw1t + (wid * 16 + m) * KPAD + q * 8;
#pragma unroll
    for (int Ks = 0; Ks < NKS; ++Ks) {
        v8s bv = *(const v8s*)(Bb + Ks * 32);
        v8s a[4];
#pragma unroll
        for (int Mt = 0; Mt < 4; ++Mt)
            a[Mt] = *(const v8s*)&tile[Mt * 16 + m][Ks * 32 + q * 8];
#pragma unroll
        for (int Mt = 0; Mt < 4; ++Mt)
            acc[Mt] = __builtin_amdgcn_mfma_f32_16x16x32_bf16(a[Mt], bv, acc[Mt], 0, 0, 0);
    }
    __syncthreads();   // all tile reads done before Hg overlay

    int c = wid * 16 + m;
    float bias = gb1[c];
#pragma unroll
    for (int Mt = 0; Mt < 4; ++Mt)
#pragma unroll
        for (int j = 0; j < 4; ++j) {
            int item = Mt * 16 + q * 4 + j;
            float v = fmaxf(acc[Mt][j] + bias, 0.f);
            Hg[item][c ^ ((item & 7) << 3)] = f2bf(v);
        }
    __syncthreads();   // Hg ready

    if (wid == 0) {
        float z[KEXP];
#pragma unroll
        for (int j = 0; j < KEXP; ++j) z[j] = gb2[j];
#pragma unroll
        for (int u = 0; u < 8; ++u) {
            v8s hv = *(const v8s*)&Hg[l][(u * 8) ^ ((l & 7) << 3)];
#pragma unroll
            for (int e = 0; e < 8; ++e) {
                int h = u * 8 + e;
                float g = bf2f((unsigned short)hv[e]);
#pragma unroll
                for (int j = 0; j < KEXP; ++j) z[j] = fmaf(g, gw2[h * KEXP + j], z[j]);
            }
        }
        float mm = z[0];
#pragma unroll
        for (int j = 1; j < KEXP; ++j) mm = fmaxf(mm, z[j]);
        float s = 0.f;
#pragma unroll
        for (int j = 0; j < KEXP; ++j) s += expf(z[j] - mm);
        int i0 = 0; float m0 = z[0];
#pragma unroll
        for (int j = 1; j < KEXP; ++j) if (z[j] > m0) { m0 = z[j]; i0 = j; }
        int i1 = (i0 == 0) ? 1 : 0; float m1 = -3.4e38f;
#pragma unroll
        for (int j = 0; j < KEXP; ++j) if (j != i0 && z[j] > m1) { m1 = z[j]; i1 = j; }
        float v0 = expf(m0 - mm) / s, v1 = expf(m1 - mm) / s;
        float inv = 1.f / (v0 + v1 + 1e-9f);
        float w0 = v0 * inv, w1 = v1 * inv;

        atomicAdd(&s_imp[i0], w0);
        atomicAdd(&s_imp[i1], w1);
        int o0 = atomicAdd(&s_cnt[i0], 1);
        int o1 = atomicAdd(&s_cnt[i1], 1);
        // stash per-lane results in registers; list write after reservation
        __syncthreads();   // wave0 atomics visible
        if (l < KEXP) s_base[l] = atomicAdd(&gcnt[l], s_cnt[l]);
        __syncthreads();
        int b = b0 + l;
        int p0 = i0 * BB + s_base[i0] + o0;
        lidx[p0] = (b << 1);     lw[p0] = w0;
        int p1 = i1 * BB + s_base[i1] + o1;
        lidx[p1] = (b << 1) | 1; lw[p1] = w1;
    } else {
        __syncthreads();
        __syncthreads();
    }
    __syncthreads();
    if (tid < KEXP) imp_part[blockIdx.x * KEXP + tid] = s_imp[tid];
}

// ---------------- pad each expert list to multiple of 64 with benign entries ----------------
__global__ void k_pad(const int* __restrict__ gcnt, int* __restrict__ lidx,
                      float* __restrict__ lw)
{
    int k = blockIdx.x;
    int n = gcnt[k];
    int ne = (n + 63) & ~63;
    for (int i = n + threadIdx.x; i < ne; i += 64) {
        lidx[k * BB + i] = 2 * BB;   // dedicated pad row
        lw[k * BB + i] = 0.f;
    }
}

// ---------------- loss ----------------
__global__ __launch_bounds__(256) void k_loss(const float* __restrict__ imp_part,
                                              float* __restrict__ out)
{
    __shared__ double sred[16][17];
    __shared__ double simp[KEXP];
    int tid = threadIdx.x;
    int j = tid & 15, g = tid >> 4;
    double s = 0.0;
    for (int blk = g; blk < NBLK_GATE; blk += 16) s += (double)imp_part[blk * KEXP + j];
    sred[g][j] = s;
    __syncthreads();
    if (tid < KEXP) {
        double t = 0.0;
#pragma unroll
        for (int gg = 0; gg < 16; ++gg) t += sred[gg][tid];
        simp[tid] = t;
    }
    __syncthreads();
    if (tid == 0) {
        double mean = 0.0;
        for (int jj = 0; jj < KEXP; ++jj) mean += simp[jj];
        mean /= KEXP;
        double var = 0.0;
        for (int jj = 0; jj < KEXP; ++jj) { double d = simp[jj] - mean; var += d * d; }
        var /= KEXP;
        out[BB] = (float)(var / (mean * mean + 1e-10));
    }
}

// ---------------- fused expert: MFMA L1 -> LDS -> MFMA L2 -> hs (bf16) ----------------
__global__ __launch_bounds__(256, 2) void k_exp(
    const unsigned short* __restrict__ xembT,
    const unsigned short* __restrict__ w1t, const unsigned short* __restrict__ w2t,
    const float* __restrict__ sc1, const float* __restrict__ sh1,
    const float* __restrict__ sc2, const float* __restrict__ sh2,
    const int* __restrict__ lidx, const float* __restrict__ lw,
    const int* __restrict__ gcnt, unsigned short* __restrict__ hs)
{
    __shared__ unsigned short Hl[4][64][80];
    int k = blockIdx.y;
    int tid = threadIdx.x;
    int wid = tid >> 6, l = tid & 63;
    int m = l & 15, q = l >> 4;
    int n = gcnt[k];
    int ne = (n + 63) & ~63;
    const unsigned short* W1 = w1t + (size_t)k * 64 * KPAD + m * KPAD + q * 8;
    const unsigned short* W2 = w2t + (size_t)k * 64 * 64 + m * 64 + q * 8;
    float sc1v[4], sh1v[4], sc2v[4], sh2v[4];
#pragma unroll
    for (int Nt = 0; Nt < 4; ++Nt) {
        int c = Nt * 16 + m;
        sc1v[Nt] = sc1[k * HID + c]; sh1v[Nt] = sh1[k * HID + c];
        sc2v[Nt] = sc2[k * HID + c]; sh2v[Nt] = sh2[k * HID + c];
    }
    v4f zero4 = {0.f, 0.f, 0.f, 0.f};

    for (int it0 = (blockIdx.x * 4 + wid) * 64; it0 < ne; it0 += NBX_EXP * 256) {
        // ---- layer 1 ----
        int eA[4];
#pragma unroll
        for (int Mt = 0; Mt < 4; ++Mt) eA[Mt] = lidx[k * BB + it0 + Mt * 16 + m];
        v4f acc1[4][4];
#pragma unroll
        for (int a = 0; a < 4; ++a)
#pragma unroll
            for (int c = 0; c < 4; ++c) acc1[a][c] = zero4;
#pragma unroll
        for (int Ks = 0; Ks < NKS; ++Ks) {
            v8s a[4], b[4];
#pragma unroll
            for (int Mt = 0; Mt < 4; ++Mt)
                a[Mt] = *(const v8s*)(xembT + (size_t)(eA[Mt] >> 1) * KPAD + Ks * 32 + q * 8);
#pragma unroll
            for (int Nt = 0; Nt < 4; ++Nt)
                b[Nt] = *(const v8s*)(W1 + Nt * 16 * KPAD + Ks * 32);
#pragma unroll
            for (int Mt = 0; Mt < 4; ++Mt)
#pragma unroll
                for (int Nt = 0; Nt < 4; ++Nt)
                    acc1[Mt][Nt] = __builtin_amdgcn_mfma_f32_16x16x32_bf16(a[Mt], b[Nt], acc1[Mt][Nt], 0, 0, 0);
        }
        // BN1 + relu -> swizzled LDS
#pragma unroll
        for (int Nt = 0; Nt < 4; ++Nt) {
            int c = Nt * 16 + m;
#pragma unroll
            for (int Mt = 0; Mt < 4; ++Mt)
#pragma unroll
                for (int j = 0; j < 4; ++j) {
                    int item = Mt * 16 + q * 4 + j;
                    float v = fmaxf(fmaf(acc1[Mt][Nt][j], sc1v[Nt], sh1v[Nt]), 0.f);
                    Hl[wid][item][c ^ ((item & 7) << 3)] = f2bf(v);
                }
        }
        // ---- layer 2 (K=64) ----
        v4f acc2[4][4];
#pragma unroll
        for (int a = 0; a < 4; ++a)
#pragma unroll
            for (int c = 0; c < 4; ++c) acc2[a][c] = zero4;
#pragma unroll
        for (int Ks = 0; Ks < 2; ++Ks) {
            v8s a[4], b[4];
#pragma unroll
            for (int Mt = 0; Mt < 4; ++Mt)
                a[Mt] = *(const v8s*)&Hl[wid][Mt * 16 + m][(Ks * 32 + q * 8) ^ ((m & 7) << 3)];
#pragma unroll
            for (int Nt = 0; Nt < 4; ++Nt)
                b[Nt] = *(const v8s*)(W2 + Nt * 16 * 64 + Ks * 32);
#pragma unroll
            for (int Mt = 0; Mt < 4; ++Mt)
#pragma unroll
                for (int Nt = 0; Nt < 4; ++Nt)
                    acc2[Mt][Nt] = __builtin_amdgcn_mfma_f32_16x16x32_bf16(a[Mt], b[Nt], acc2[Mt][Nt], 0, 0, 0);
        }
        // BN2 + relu, * gate weight -> swizzled LDS (reuse)
#pragma unroll
        for (int Mt = 0; Mt < 4; ++Mt) {
            float4 wC = *(const float4*)&lw[k * BB + it0 + Mt * 16 + q * 4];
            float wj[4] = {wC.x, wC.y, wC.z, wC.w};
#pragma unroll
            for (int Nt = 0; Nt < 4; ++Nt) {
                int c = Nt * 16 + m;
#pragma unroll
                for (int j = 0; j < 4; ++j) {
                    int item = Mt * 16 + q * 4 + j;
                    float v = wj[j] * fmaxf(fmaf(acc2[Mt][Nt][j], sc2v[Nt], sh2v[Nt]), 0.f);
                    Hl[wid][item][c ^ ((item & 7) << 3)] = f2bf(v);
                }
            }
        }
        // per-lane: write own row to hs[e][64] (coalesced 16B chunks)
        int eo = lidx[k * BB + it0 + l];
        unsigned short* hrow = hs + (size_t)eo * HID;
#pragma unroll
        for (int u = 0; u < 8; ++u)
            *(v8s*)(hrow + u * 8) = *(const v8s*)&Hl[wid][l][(u * 8) ^ ((l & 7) << 3)];
    }
}

// ---------------- head: sum slots + MFMA (K=64) + BN/relu + dot pw2 ----------------
__global__ __launch_bounds__(256, 2) void k_head(
    const unsigned short* __restrict__ hs, const unsigned short* __restrict__ pw1t,
    const float* __restrict__ scp, const float* __restrict__ shp,
    const float* __restrict__ pw2, const float* __restrict__ pb2,
    float* __restrict__ out)
{
    int tid = threadIdx.x;
    int wid = tid >> 6, l = tid & 63;
    int m = l & 15, q = l >> 4;
    int it0 = blockIdx.x * 256 + wid * 64;
    float scv[4], shv[4], w2v[4];
#pragma unroll
    for (int Nt = 0; Nt < 4; ++Nt) {
        int c = Nt * 16 + m;
        scv[Nt] = scp[c]; shv[Nt] = shp[c]; w2v[Nt] = pw2[c];
    }
    v4f zero4 = {0.f, 0.f, 0.f, 0.f};
    v4f acc[4][4];
#pragma unroll
    for (int a = 0; a < 4; ++a)
#pragma unroll
        for (int c = 0; c < 4; ++c) acc[a][c] = zero4;

#pragma unroll
    for (int Ks = 0; Ks < 2; ++Ks) {
        v8s a[4], b[4];
#pragma unroll
        for (int Mt = 0; Mt < 4; ++Mt) {
            int bi = it0 + Mt * 16 + m;
            const unsigned short* r0 = hs + (size_t)(2 * bi) * HID + Ks * 32 + q * 8;
            v8s u0 = *(const v8s*)r0;
            v8s u1 = *(const v8s*)(r0 + HID);
            v8s av;
#pragma unroll
            for (int e = 0; e < 8; ++e) {
                float f = bf2f((unsigned short)u0[e]) + bf2f((unsigned short)u1[e]);
                av[e] = (short)f2bf(f);
            }
            a[Mt] = av;
        }
#pragma unroll
        for (int Nt = 0; Nt < 4; ++Nt)
            b[Nt] = *(const v8s*)(pw1t + (Nt * 16 + m) * HID + Ks * 32 + q * 8);
#pragma unroll
        for (int Mt = 0; Mt < 4; ++Mt)
#pragma unroll
            for (int Nt = 0; Nt < 4; ++Nt)
                acc[Mt][Nt] = __builtin_amdgcn_mfma_f32_16x16x32_bf16(a[Mt], b[Nt], acc[Mt][Nt], 0, 0, 0);
    }
    float pb2v = pb2[0];
#pragma unroll
    for (int Mt = 0; Mt < 4; ++Mt) {
#pragma unroll
        for (int j = 0; j < 4; ++j) {
            float po = 0.f;
#pragma unroll
            for (int Nt = 0; Nt < 4; ++Nt) {
                float ph = fmaxf(fmaf(acc[Mt][Nt][j], scv[Nt], shv[Nt]), 0.f);
                po = fmaf(ph, w2v[Nt], po);
            }
            po += __shfl_xor(po, 1);
            po += __shfl_xor(po, 2);
            po += __shfl_xor(po, 4);
            po += __shfl_xor(po, 8);
            if (m == 0) out[it0 + Mt * 16 + q * 4 + j] = po + pb2v;
        }
    }
}

extern "C" void kernel_launch(void* const* d_in, const int* in_sizes, int n_in,
                              void* d_out, int out_size, void* d_ws, size_t ws_size,
                              hipStream_t stream) {
    const int*   x     = (const int*)d_in[0];
    const int*   sql   = (const int*)d_in[1];
    const float* itab  = (const float*)d_in[2];
    const float* stab  = (const float*)d_in[3];
    const float* gw1   = (const float*)d_in[4];
    const float* gb1   = (const float*)d_in[5];
    const float* gw2   = (const float*)d_in[6];
    const float* gb2   = (const float*)d_in[7];
    const float* ew1   = (const float*)d_in[8];
    const float* eb1   = (const float*)d_in[9];
    const float* eg1   = (const float*)d_in[10];
    const float* ebe1  = (const float*)d_in[11];
    const float* em1   = (const float*)d_in[12];
    const float* ev1   = (const float*)d_in[13];
    const float* ew2   = (const float*)d_in[14];
    const float* eb2   = (const float*)d_in[15];
    const float* eg2   = (const float*)d_in[16];
    const float* ebe2  = (const float*)d_in[17];
    const float* em2   = (const float*)d_in[18];
    const float* ev2   = (const float*)d_in[19];
    const float* pw1   = (const float*)d_in[20];
    const float* pb1   = (const float*)d_in[21];
    const float* pg    = (const float*)d_in[22];
    const float* pbe   = (const float*)d_in[23];
    const float* pm    = (const float*)d_in[24];
    const float* pv    = (const float*)d_in[25];
    const float* pw2   = (const float*)d_in[26];
    const float* pb2   = (const float*)d_in[27];

    float* wsf = (float*)d_ws;
    int*   wsi = (int*)d_ws;
    int*   gcnt = wsi + OFF_GCNT;
    float* sc1 = wsf + OFF_SC1;
    float* sh1 = wsf + OFF_SH1;
    float* sc2 = wsf + OFF_SC2;
    float* sh2 = wsf + OFF_SH2;
    float* scp = wsf + OFF_SCP;
    float* shp = wsf + OFF_SHP;
    float* imp = wsf + OFF_IMP;
    int*   lidx = wsi + OFF_LIDX;
    float* lw  = wsf + OFF_LW;
    unsigned short* w1t   = (unsigned short*)(wsf + OFF_W1T);
    unsigned short* gw1t  = (unsigned short*)(wsf + OFF_GW1T);
    unsigned short* w2t   = (unsigned short*)(wsf + OFF_W2T);
    unsigned short* pw1t  = (unsigned short*)(wsf + OFF_PW1T);
    unsigned short* xembT = (unsigned short*)(wsf + OFF_XEMB);
    unsigned short* hs    = (unsigned short*)(wsf + OFF_HS);
    float* out = (float*)d_out;

    k_prep<<<1229, 256, 0, stream>>>(ew1, ew2, gw1, pw1,
                                     eb1, eg1, ebe1, em1, ev1,
                                     eb2, eg2, ebe2, em2, ev2,
                                     pb1, pg, pbe, pm, pv,
                                     wsf, gcnt, w1t, gw1t, w2t, pw1t);
    k_emb<<<BB / EMB_BPB, 256, 0, stream>>>(x, itab, xembT);
    k_gate<<<NBLK_GATE, 256, 0, stream>>>(sql, stab, gw1t, gb1, gw2, gb2,
                                          lidx, lw, gcnt, imp);
    k_loss<<<1, 256, 0, stream>>>(imp, out);
    k_pad<<<16, 64, 0, stream>>>(gcnt, lidx, lw);
    dim3 ge(NBX_EXP, KEXP);
    k_exp<<<ge, 256, 0, stream>>>(xembT, w1t, w2t, sc1, sh1, sc2, sh2,
                                  lidx, lw, gcnt, hs);
    k_head<<<256, 256, 0, stream>>>(hs, pw1t, scp, shp, pw2, pb2, out);
}